// Round 1
// baseline (1281.609 us; speedup 1.0000x reference)
//
#include <hip/hip_runtime.h>
#include <math.h>

#define NFRAME 96
#define NTOK   197
#define NSPAT  196
#define DIM    512
#define DH     256
#define NSAMP  256
#define KSEL   49
#define SIG    0.05f

#define T_ROWS 16
#define TILES  13   // ceil(197/16)

__device__ __forceinline__ float gelu_exact(float v) {
    return 0.5f * v * (1.0f + erff(v * 0.70710678118654752440f));
}

// ---------------------------------------------------------------------------
// K1: LayerNorm + MLP + tanh score, fp32 vector ALU.
// grid = 96 frames x 13 row-tiles, block = 256 threads (4 waves).
// Each wave owns 4 rows; each lane owns 4 consecutive output columns.
// ---------------------------------------------------------------------------
__global__ __launch_bounds__(256, 2) void k1_scores(
    const float* __restrict__ x, const float* __restrict__ gamma,
    const float* __restrict__ beta, const float* __restrict__ w_in,
    const float* __restrict__ w1, const float* __restrict__ w2,
    float* __restrict__ sp)
{
    const int f    = blockIdx.x / TILES;
    const int tile = blockIdx.x - f * TILES;
    const int r0   = tile * T_ROWS;
    const int t    = threadIdx.x;
    const int lane = t & 63;
    const int wv   = t >> 6;       // wave id 0..3
    const int c0   = lane * 4;     // output column group
    const int rb   = wv * 4;       // local row base

    __shared__ __align__(16) float hn_s[T_ROWS][DIM];   // 32 KB
    __shared__ __align__(16) float hn0_s[DIM];          // 2 KB
    __shared__ __align__(16) float cat_s[T_ROWS][DIM];  // 32 KB: [0:256)=h, [256:512)=h0
    __shared__ __align__(16) float wt_s[8 * DH];        // 8 KB k-tile of weights

    float gam[8], bet[8];
    #pragma unroll
    for (int j = 0; j < 8; ++j) {
        gam[j] = gamma[lane + 64 * j];
        bet[j] = beta[lane + 64 * j];
    }

    auto ln_row = [&](const float* xr, float* dst) {
        float v[8]; float s = 0.f, sq = 0.f;
        #pragma unroll
        for (int j = 0; j < 8; ++j) {
            float a = xr[lane + 64 * j];
            v[j] = a; s += a; sq += a * a;
        }
        #pragma unroll
        for (int o = 32; o > 0; o >>= 1) {
            s  += __shfl_xor(s,  o, 64);
            sq += __shfl_xor(sq, o, 64);
        }
        float mu   = s * (1.f / 512.f);
        float var  = sq * (1.f / 512.f) - mu * mu;
        float rstd = 1.f / sqrtf(var + 1e-5f);
        #pragma unroll
        for (int j = 0; j < 8; ++j)
            dst[lane + 64 * j] = (v[j] - mu) * rstd * gam[j] + bet[j];
    };

    // LayerNorm: wave wv handles local rows wv, wv+4, wv+8, wv+12; wave 0 also row0
    for (int rr = wv; rr < T_ROWS; rr += 4) {
        int gr = r0 + rr; if (gr > NTOK - 1) gr = NTOK - 1;  // clamp partial tile
        ln_row(x + ((size_t)f * NTOK + gr) * DIM, &hn_s[rr][0]);
    }
    if (wv == 0) ln_row(x + (size_t)f * NTOK * DIM, hn0_s);
    __syncthreads();

    // ---------------- GEMM1: h = gelu(hn @ w_in), plus row0 (for g) ----------------
    float acc[4][4] = {};
    float acc0[4]   = {};
    for (int kt = 0; kt < DIM; kt += 8) {
        __syncthreads();
        {   // stage w_in[kt..kt+8)[0..256) -> wt_s (512 float4, 2 per thread)
            const float4* srcv = (const float4*)(w_in + (size_t)kt * DH);
            float4* dstv = (float4*)wt_s;
            dstv[t]       = srcv[t];
            dstv[t + 256] = srcv[t + 256];
        }
        __syncthreads();
        #pragma unroll
        for (int i4 = 0; i4 < 2; ++i4) {
            const int k0 = i4 * 4;
            float A[5][4];
            *(float4*)A[0] = *(const float4*)&hn_s[rb + 0][kt + k0];
            *(float4*)A[1] = *(const float4*)&hn_s[rb + 1][kt + k0];
            *(float4*)A[2] = *(const float4*)&hn_s[rb + 2][kt + k0];
            *(float4*)A[3] = *(const float4*)&hn_s[rb + 3][kt + k0];
            *(float4*)A[4] = *(const float4*)&hn0_s[kt + k0];
            #pragma unroll
            for (int ii = 0; ii < 4; ++ii) {
                float4 w4 = *(const float4*)&wt_s[(k0 + ii) * DH + c0];
                #pragma unroll
                for (int r = 0; r < 4; ++r) {
                    acc[r][0] += A[r][ii] * w4.x;
                    acc[r][1] += A[r][ii] * w4.y;
                    acc[r][2] += A[r][ii] * w4.z;
                    acc[r][3] += A[r][ii] * w4.w;
                }
                acc0[0] += A[4][ii] * w4.x;
                acc0[1] += A[4][ii] * w4.y;
                acc0[2] += A[4][ii] * w4.z;
                acc0[3] += A[4][ii] * w4.w;
            }
        }
    }

    // gelu + write cat = [h | h0]
    #pragma unroll
    for (int r = 0; r < 4; ++r) {
        float4 hv = make_float4(gelu_exact(acc[r][0]), gelu_exact(acc[r][1]),
                                gelu_exact(acc[r][2]), gelu_exact(acc[r][3]));
        *(float4*)&cat_s[rb + r][c0] = hv;
    }
    {
        float4 g4 = make_float4(gelu_exact(acc0[0]), gelu_exact(acc0[1]),
                                gelu_exact(acc0[2]), gelu_exact(acc0[3]));
        #pragma unroll
        for (int r = 0; r < 4; ++r)
            *(float4*)&cat_s[rb + r][DH + c0] = g4;
    }

    // ---------------- GEMM2: s2 = cat @ w1 ----------------
    float acc2[4][4] = {};
    for (int kt = 0; kt < DIM; kt += 8) {
        __syncthreads();   // also guards cat_s writes before first read
        {
            const float4* srcv = (const float4*)(w1 + (size_t)kt * DH);
            float4* dstv = (float4*)wt_s;
            dstv[t]       = srcv[t];
            dstv[t + 256] = srcv[t + 256];
        }
        __syncthreads();
        #pragma unroll
        for (int i4 = 0; i4 < 2; ++i4) {
            const int k0 = i4 * 4;
            float A[4][4];
            *(float4*)A[0] = *(const float4*)&cat_s[rb + 0][kt + k0];
            *(float4*)A[1] = *(const float4*)&cat_s[rb + 1][kt + k0];
            *(float4*)A[2] = *(const float4*)&cat_s[rb + 2][kt + k0];
            *(float4*)A[3] = *(const float4*)&cat_s[rb + 3][kt + k0];
            #pragma unroll
            for (int ii = 0; ii < 4; ++ii) {
                float4 w4 = *(const float4*)&wt_s[(k0 + ii) * DH + c0];
                #pragma unroll
                for (int r = 0; r < 4; ++r) {
                    acc2[r][0] += A[r][ii] * w4.x;
                    acc2[r][1] += A[r][ii] * w4.y;
                    acc2[r][2] += A[r][ii] * w4.z;
                    acc2[r][3] += A[r][ii] * w4.w;
                }
            }
        }
    }

    // score = tanh(gelu(s2) @ w2) — wave-reduce over the 64 column lanes
    float4 w2v = *(const float4*)&w2[c0];
    float p[4];
    #pragma unroll
    for (int r = 0; r < 4; ++r) {
        p[r] = gelu_exact(acc2[r][0]) * w2v.x + gelu_exact(acc2[r][1]) * w2v.y +
               gelu_exact(acc2[r][2]) * w2v.z + gelu_exact(acc2[r][3]) * w2v.w;
    }
    #pragma unroll
    for (int o = 32; o > 0; o >>= 1) {
        p[0] += __shfl_xor(p[0], o, 64);
        p[1] += __shfl_xor(p[1], o, 64);
        p[2] += __shfl_xor(p[2], o, 64);
        p[3] += __shfl_xor(p[3], o, 64);
    }
    if (lane == 0) {
        #pragma unroll
        for (int r = 0; r < 4; ++r) {
            int gr = r0 + rb + r;
            if (gr >= 1 && gr < NTOK)
                sp[f * NSPAT + gr - 1] = tanhf(p[r]);
        }
    }
}

// ---------------------------------------------------------------------------
// K2: per-sample top-49 selection via 32-bit radix descent on ordered keys,
// then index-rank + histogram scatter. One wave per sample.
// ---------------------------------------------------------------------------
__global__ __launch_bounds__(256) void k2_select(
    const float* __restrict__ sp, const float* __restrict__ noise,
    int* __restrict__ hist)
{
    const int wid  = blockIdx.x * 4 + (threadIdx.x >> 6);  // sample id 0..24575
    const int lane = threadIdx.x & 63;
    const int b    = wid >> 8;
    const float* nz  = noise + (size_t)wid * NSPAT;
    const float* spb = sp + (size_t)b * NSPAT;

    unsigned key[4];
    #pragma unroll
    for (int j = 0; j < 4; ++j) {
        int l = lane + 64 * j;
        if (l < NSPAT) {
            float p = spb[l] + nz[l] * SIG;
            unsigned u = __float_as_uint(p);
            key[j] = (u & 0x80000000u) ? ~u : (u | 0x80000000u);  // order-preserving map
        } else {
            key[j] = 0u;   // padding: smaller than any real key (all real keys > 0)
        }
    }

    // radix descent: ans = max t with count(key >= t) >= 49  == 49th-largest key
    unsigned ans = 0u;
    for (int bit = 31; bit >= 0; --bit) {
        unsigned cand = ans | (1u << bit);
        int cnt = 0;
        #pragma unroll
        for (int j = 0; j < 4; ++j)
            cnt += __popcll(__ballot(key[j] >= cand));
        if (cnt >= KSEL) ans = cand;
    }

    const unsigned long long lmask = (1ull << lane) - 1ull;

    // strictly-greater count and tie masks
    unsigned long long eq[4];
    int cgt = 0;
    #pragma unroll
    for (int j = 0; j < 4; ++j) {
        cgt += __popcll(__ballot(key[j] > ans));
        eq[j] = __ballot(key[j] == ans);
    }
    const int quota = KSEL - cgt;   // ties kept, lowest index first (stable argsort)

    int eqpre[4]; { int run = 0;
        #pragma unroll
        for (int j = 0; j < 4; ++j) { eqpre[j] = run; run += __popcll(eq[j]); } }

    bool selj[4];
    #pragma unroll
    for (int j = 0; j < 4; ++j) {
        bool iseq = (key[j] == ans);
        int trk = eqpre[j] + __popcll(eq[j] & lmask);
        selj[j] = (key[j] > ans) || (iseq && trk < quota);
    }

    // rank among selected by ascending token index (j-major, lane-minor) + scatter
    int pre = 0;
    #pragma unroll
    for (int j = 0; j < 4; ++j) {
        unsigned long long sb = __ballot(selj[j]);
        int rk = pre + __popcll(sb & lmask);
        if (selj[j])
            atomicAdd(&hist[((size_t)b * KSEL + rk) * NSPAT + lane + 64 * j], 1);
        pre += __popcll(sb);
    }
}

// ---------------------------------------------------------------------------
// K3: out = [cls | (hist/256) @ spat].  grid = 96 frames x 4 d-slices of 128.
// ---------------------------------------------------------------------------
#define TL3 28
__global__ __launch_bounds__(256) void k3_output(
    const float* __restrict__ x, const int* __restrict__ hist,
    float* __restrict__ out)
{
    const int b  = blockIdx.x >> 2;
    const int ds = blockIdx.x & 3;
    const int d0 = ds * 128;
    const int t  = threadIdx.x;

    __shared__ __align__(16) float hist_s[56 * NSPAT];   // zero-padded to 56 k's
    __shared__ __align__(16) float spat_s[TL3][128];

    for (int i = t; i < 56 * NSPAT; i += 256)
        hist_s[i] = (i < KSEL * NSPAT) ? (float)hist[(size_t)b * KSEL * NSPAT + i] : 0.f;

    // cls row (raw x row 0 of the frame)
    if (t < 128)
        out[(size_t)b * 50 * DIM + d0 + t] = x[(size_t)b * NTOK * DIM + d0 + t];

    const int tdc = t & 31;            // 32 float4 columns
    const int tk  = t >> 5;            // 8 k-groups
    const int dc  = d0 + tdc * 4;
    float4 acc[7];
    #pragma unroll
    for (int i = 0; i < 7; ++i) acc[i] = make_float4(0.f, 0.f, 0.f, 0.f);

    for (int lt = 0; lt < NSPAT; lt += TL3) {
        __syncthreads();
        for (int i = t; i < TL3 * 128; i += 256) {
            int l = lt + (i >> 7); int dcc = i & 127;
            spat_s[i >> 7][dcc] = x[((size_t)b * NTOK + 1 + l) * DIM + d0 + dcc];
        }
        __syncthreads();
        for (int li = 0; li < TL3; ++li) {
            float4 v = *(const float4*)&spat_s[li][tdc * 4];
            int l = lt + li;
            #pragma unroll
            for (int i = 0; i < 7; ++i) {
                float w = hist_s[(tk + 8 * i) * NSPAT + l];
                acc[i].x += w * v.x; acc[i].y += w * v.y;
                acc[i].z += w * v.z; acc[i].w += w * v.w;
            }
        }
    }

    const float inv = 1.f / 256.f;
    #pragma unroll
    for (int i = 0; i < 7; ++i) {
        int k = tk + 8 * i;
        if (k < KSEL) {
            float4 o = make_float4(acc[i].x * inv, acc[i].y * inv,
                                   acc[i].z * inv, acc[i].w * inv);
            *(float4*)&out[((size_t)b * 50 + 1 + k) * DIM + dc] = o;
        }
    }
}

// ---------------------------------------------------------------------------
extern "C" void kernel_launch(void* const* d_in, const int* in_sizes, int n_in,
                              void* d_out, int out_size, void* d_ws, size_t ws_size,
                              hipStream_t stream)
{
    const float* x     = (const float*)d_in[0];
    const float* noise = (const float*)d_in[1];
    const float* gamma = (const float*)d_in[2];
    const float* beta  = (const float*)d_in[3];
    const float* w_in  = (const float*)d_in[4];
    const float* w1    = (const float*)d_in[5];
    const float* w2    = (const float*)d_in[6];
    float* out = (float*)d_out;

    const size_t hist_bytes = (size_t)NFRAME * KSEL * NSPAT * sizeof(int);  // 3.69 MB
    int*   hist = (int*)d_ws;
    float* sp   = (float*)((char*)d_ws + hist_bytes);                       // 96*196 f32

    hipMemsetAsync(hist, 0, hist_bytes, stream);
    k1_scores<<<NFRAME * TILES, 256, 0, stream>>>(x, gamma, beta, w_in, w1, w2, sp);
    k2_select<<<NFRAME * NSAMP / 4, 256, 0, stream>>>(sp, noise, hist);
    k3_output<<<NFRAME * 4, 256, 0, stream>>>(x, hist, out);
}

// Round 2
// 452.701 us; speedup vs baseline: 2.8310x; 2.8310x over previous
//
#include <hip/hip_runtime.h>
#include <math.h>

#define NFRAME 96
#define NTOK   197
#define NSPAT  196
#define DIM    512
#define DH     256
#define NSAMP  256
#define KSEL   49
#define SIG    0.05f

#define T_ROWS 16
#define TILES  13   // ceil(197/16)

__device__ __forceinline__ float gelu_exact(float v) {
    return 0.5f * v * (1.0f + erff(v * 0.70710678118654752440f));
}

// ---------------------------------------------------------------------------
// K1: LayerNorm + MLP + tanh score, fp32 vector ALU.
// grid = 96 frames x 13 row-tiles, block = 256 threads (4 waves).
// Each wave owns 4 rows; each lane owns 4 consecutive output columns.
// ---------------------------------------------------------------------------
__global__ __launch_bounds__(256, 2) void k1_scores(
    const float* __restrict__ x, const float* __restrict__ gamma,
    const float* __restrict__ beta, const float* __restrict__ w_in,
    const float* __restrict__ w1, const float* __restrict__ w2,
    float* __restrict__ sp)
{
    const int f    = blockIdx.x / TILES;
    const int tile = blockIdx.x - f * TILES;
    const int r0   = tile * T_ROWS;
    const int t    = threadIdx.x;
    const int lane = t & 63;
    const int wv   = t >> 6;       // wave id 0..3
    const int c0   = lane * 4;     // output column group
    const int rb   = wv * 4;       // local row base

    __shared__ __align__(16) float hn_s[T_ROWS][DIM];   // 32 KB
    __shared__ __align__(16) float hn0_s[DIM];          // 2 KB
    __shared__ __align__(16) float cat_s[T_ROWS][DIM];  // 32 KB: [0:256)=h, [256:512)=h0
    __shared__ __align__(16) float wt_s[8 * DH];        // 8 KB k-tile of weights

    float gam[8], bet[8];
    #pragma unroll
    for (int j = 0; j < 8; ++j) {
        gam[j] = gamma[lane + 64 * j];
        bet[j] = beta[lane + 64 * j];
    }

    auto ln_row = [&](const float* xr, float* dst) {
        float v[8]; float s = 0.f, sq = 0.f;
        #pragma unroll
        for (int j = 0; j < 8; ++j) {
            float a = xr[lane + 64 * j];
            v[j] = a; s += a; sq += a * a;
        }
        #pragma unroll
        for (int o = 32; o > 0; o >>= 1) {
            s  += __shfl_xor(s,  o, 64);
            sq += __shfl_xor(sq, o, 64);
        }
        float mu   = s * (1.f / 512.f);
        float var  = sq * (1.f / 512.f) - mu * mu;
        float rstd = 1.f / sqrtf(var + 1e-5f);
        #pragma unroll
        for (int j = 0; j < 8; ++j)
            dst[lane + 64 * j] = (v[j] - mu) * rstd * gam[j] + bet[j];
    };

    // LayerNorm: wave wv handles local rows wv, wv+4, wv+8, wv+12; wave 0 also row0
    for (int rr = wv; rr < T_ROWS; rr += 4) {
        int gr = r0 + rr; if (gr > NTOK - 1) gr = NTOK - 1;  // clamp partial tile
        ln_row(x + ((size_t)f * NTOK + gr) * DIM, &hn_s[rr][0]);
    }
    if (wv == 0) ln_row(x + (size_t)f * NTOK * DIM, hn0_s);
    __syncthreads();

    // ---------------- GEMM1: h = gelu(hn @ w_in), plus row0 (for g) ----------------
    float acc[4][4] = {};
    float acc0[4]   = {};
    for (int kt = 0; kt < DIM; kt += 8) {
        __syncthreads();
        {   // stage w_in[kt..kt+8)[0..256) -> wt_s (512 float4, 2 per thread)
            const float4* srcv = (const float4*)(w_in + (size_t)kt * DH);
            float4* dstv = (float4*)wt_s;
            dstv[t]       = srcv[t];
            dstv[t + 256] = srcv[t + 256];
        }
        __syncthreads();
        #pragma unroll
        for (int i4 = 0; i4 < 2; ++i4) {
            const int k0 = i4 * 4;
            float A[5][4];
            *(float4*)A[0] = *(const float4*)&hn_s[rb + 0][kt + k0];
            *(float4*)A[1] = *(const float4*)&hn_s[rb + 1][kt + k0];
            *(float4*)A[2] = *(const float4*)&hn_s[rb + 2][kt + k0];
            *(float4*)A[3] = *(const float4*)&hn_s[rb + 3][kt + k0];
            *(float4*)A[4] = *(const float4*)&hn0_s[kt + k0];
            #pragma unroll
            for (int ii = 0; ii < 4; ++ii) {
                float4 w4 = *(const float4*)&wt_s[(k0 + ii) * DH + c0];
                #pragma unroll
                for (int r = 0; r < 4; ++r) {
                    acc[r][0] += A[r][ii] * w4.x;
                    acc[r][1] += A[r][ii] * w4.y;
                    acc[r][2] += A[r][ii] * w4.z;
                    acc[r][3] += A[r][ii] * w4.w;
                }
                acc0[0] += A[4][ii] * w4.x;
                acc0[1] += A[4][ii] * w4.y;
                acc0[2] += A[4][ii] * w4.z;
                acc0[3] += A[4][ii] * w4.w;
            }
        }
    }

    // gelu + write cat = [h | h0]
    #pragma unroll
    for (int r = 0; r < 4; ++r) {
        float4 hv = make_float4(gelu_exact(acc[r][0]), gelu_exact(acc[r][1]),
                                gelu_exact(acc[r][2]), gelu_exact(acc[r][3]));
        *(float4*)&cat_s[rb + r][c0] = hv;
    }
    {
        float4 g4 = make_float4(gelu_exact(acc0[0]), gelu_exact(acc0[1]),
                                gelu_exact(acc0[2]), gelu_exact(acc0[3]));
        #pragma unroll
        for (int r = 0; r < 4; ++r)
            *(float4*)&cat_s[rb + r][DH + c0] = g4;
    }

    // ---------------- GEMM2: s2 = cat @ w1 ----------------
    float acc2[4][4] = {};
    for (int kt = 0; kt < DIM; kt += 8) {
        __syncthreads();   // also guards cat_s writes before first read
        {
            const float4* srcv = (const float4*)(w1 + (size_t)kt * DH);
            float4* dstv = (float4*)wt_s;
            dstv[t]       = srcv[t];
            dstv[t + 256] = srcv[t + 256];
        }
        __syncthreads();
        #pragma unroll
        for (int i4 = 0; i4 < 2; ++i4) {
            const int k0 = i4 * 4;
            float A[4][4];
            *(float4*)A[0] = *(const float4*)&cat_s[rb + 0][kt + k0];
            *(float4*)A[1] = *(const float4*)&cat_s[rb + 1][kt + k0];
            *(float4*)A[2] = *(const float4*)&cat_s[rb + 2][kt + k0];
            *(float4*)A[3] = *(const float4*)&cat_s[rb + 3][kt + k0];
            #pragma unroll
            for (int ii = 0; ii < 4; ++ii) {
                float4 w4 = *(const float4*)&wt_s[(k0 + ii) * DH + c0];
                #pragma unroll
                for (int r = 0; r < 4; ++r) {
                    acc2[r][0] += A[r][ii] * w4.x;
                    acc2[r][1] += A[r][ii] * w4.y;
                    acc2[r][2] += A[r][ii] * w4.z;
                    acc2[r][3] += A[r][ii] * w4.w;
                }
            }
        }
    }

    // score = tanh(gelu(s2) @ w2) — wave-reduce over the 64 column lanes
    float4 w2v = *(const float4*)&w2[c0];
    float p[4];
    #pragma unroll
    for (int r = 0; r < 4; ++r) {
        p[r] = gelu_exact(acc2[r][0]) * w2v.x + gelu_exact(acc2[r][1]) * w2v.y +
               gelu_exact(acc2[r][2]) * w2v.z + gelu_exact(acc2[r][3]) * w2v.w;
    }
    #pragma unroll
    for (int o = 32; o > 0; o >>= 1) {
        p[0] += __shfl_xor(p[0], o, 64);
        p[1] += __shfl_xor(p[1], o, 64);
        p[2] += __shfl_xor(p[2], o, 64);
        p[3] += __shfl_xor(p[3], o, 64);
    }
    if (lane == 0) {
        #pragma unroll
        for (int r = 0; r < 4; ++r) {
            int gr = r0 + rb + r;
            if (gr >= 1 && gr < NTOK)
                sp[f * NSPAT + gr - 1] = tanhf(p[r]);
        }
    }
}

// ---------------------------------------------------------------------------
// K2: per-sample top-49 selection via 32-bit radix descent on ordered keys,
// then index-rank + histogram scatter. One wave per sample.
// ---------------------------------------------------------------------------
__global__ __launch_bounds__(256) void k2_select(
    const float* __restrict__ sp, const float* __restrict__ noise,
    int* __restrict__ hist)
{
    const int wid  = blockIdx.x * 4 + (threadIdx.x >> 6);  // sample id 0..24575
    const int lane = threadIdx.x & 63;
    const int b    = wid >> 8;
    const float* nz  = noise + (size_t)wid * NSPAT;
    const float* spb = sp + (size_t)b * NSPAT;

    unsigned key[4];
    #pragma unroll
    for (int j = 0; j < 4; ++j) {
        int l = lane + 64 * j;
        if (l < NSPAT) {
            float p = spb[l] + nz[l] * SIG;
            unsigned u = __float_as_uint(p);
            key[j] = (u & 0x80000000u) ? ~u : (u | 0x80000000u);  // order-preserving map
        } else {
            key[j] = 0u;   // padding: smaller than any real key (all real keys > 0)
        }
    }

    // radix descent: ans = max t with count(key >= t) >= 49  == 49th-largest key
    unsigned ans = 0u;
    for (int bit = 31; bit >= 0; --bit) {
        unsigned cand = ans | (1u << bit);
        int cnt = 0;
        #pragma unroll
        for (int j = 0; j < 4; ++j)
            cnt += __popcll(__ballot(key[j] >= cand));
        if (cnt >= KSEL) ans = cand;
    }

    const unsigned long long lmask = (1ull << lane) - 1ull;

    // strictly-greater count and tie masks
    unsigned long long eq[4];
    int cgt = 0;
    #pragma unroll
    for (int j = 0; j < 4; ++j) {
        cgt += __popcll(__ballot(key[j] > ans));
        eq[j] = __ballot(key[j] == ans);
    }
    const int quota = KSEL - cgt;   // ties kept, lowest index first (stable argsort)

    int eqpre[4]; { int run = 0;
        #pragma unroll
        for (int j = 0; j < 4; ++j) { eqpre[j] = run; run += __popcll(eq[j]); } }

    bool selj[4];
    #pragma unroll
    for (int j = 0; j < 4; ++j) {
        bool iseq = (key[j] == ans);
        int trk = eqpre[j] + __popcll(eq[j] & lmask);
        selj[j] = (key[j] > ans) || (iseq && trk < quota);
    }

    // rank among selected by ascending token index (j-major, lane-minor) + scatter
    int pre = 0;
    #pragma unroll
    for (int j = 0; j < 4; ++j) {
        unsigned long long sb = __ballot(selj[j]);
        int rk = pre + __popcll(sb & lmask);
        if (selj[j])
            atomicAdd(&hist[((size_t)b * KSEL + rk) * NSPAT + lane + 64 * j], 1);
        pre += __popcll(sb);
    }
}

// ---------------------------------------------------------------------------
// K3: out = [cls | (hist/256) @ spat].  grid = 96 frames x 4 d-slices of 128.
// Spill-proof rewrite: hist in LDS (l-major for broadcast reads), spat read
// straight from global (L1 serves the 8x intra-block reuse), l-loop kept
// rolled (#pragma unroll 2) so registers stay at ~48 VGPRs.
// ---------------------------------------------------------------------------
__global__ __launch_bounds__(256) void k3_output(
    const float* __restrict__ x, const int* __restrict__ hist,
    float* __restrict__ out)
{
    const int b  = blockIdx.x >> 2;
    const int ds = blockIdx.x & 3;
    const int d0 = ds * 128;
    const int t  = threadIdx.x;
    const int tdc = t & 31;            // 32 float4 column groups
    const int tk  = t >> 5;            // 8 k-groups

    // [l][k] layout, padded so the k=49..55 ghost reads stay in-bounds
    __shared__ float hist_s[NSPAT * KSEL + 8];   // 38.4 KB

    const int* hb = hist + (size_t)b * KSEL * NSPAT;
    for (int i = t; i < KSEL * NSPAT; i += 256) {
        int k = i / NSPAT;
        int l = i - k * NSPAT;
        hist_s[l * KSEL + k] = (float)hb[i];     // transpose to l-major
    }

    // cls row (raw x row 0 of the frame)
    if (t < 128)
        out[(size_t)b * 50 * DIM + d0 + t] = x[(size_t)b * NTOK * DIM + d0 + t];
    __syncthreads();

    const float* xs = x + ((size_t)b * NTOK + 1) * DIM + d0 + tdc * 4;
    float4 acc[7];
    #pragma unroll
    for (int i = 0; i < 7; ++i) acc[i] = make_float4(0.f, 0.f, 0.f, 0.f);

    #pragma unroll 2
    for (int l = 0; l < NSPAT; ++l) {
        float4 v = *(const float4*)(xs + (size_t)l * DIM);
        const float* hl = &hist_s[l * KSEL + tk];
        #pragma unroll
        for (int i = 0; i < 7; ++i) {
            float w = hl[8 * i];                 // 2 addresses/wave -> broadcast
            acc[i].x += w * v.x; acc[i].y += w * v.y;
            acc[i].z += w * v.z; acc[i].w += w * v.w;
        }
    }

    const float inv = 1.f / 256.f;
    #pragma unroll
    for (int i = 0; i < 7; ++i) {
        int k = tk + 8 * i;
        if (k < KSEL) {
            float4 o = make_float4(acc[i].x * inv, acc[i].y * inv,
                                   acc[i].z * inv, acc[i].w * inv);
            *(float4*)&out[((size_t)b * 50 + 1 + k) * DIM + d0 + tdc * 4] = o;
        }
    }
}

// ---------------------------------------------------------------------------
extern "C" void kernel_launch(void* const* d_in, const int* in_sizes, int n_in,
                              void* d_out, int out_size, void* d_ws, size_t ws_size,
                              hipStream_t stream)
{
    const float* x     = (const float*)d_in[0];
    const float* noise = (const float*)d_in[1];
    const float* gamma = (const float*)d_in[2];
    const float* beta  = (const float*)d_in[3];
    const float* w_in  = (const float*)d_in[4];
    const float* w1    = (const float*)d_in[5];
    const float* w2    = (const float*)d_in[6];
    float* out = (float*)d_out;

    const size_t hist_bytes = (size_t)NFRAME * KSEL * NSPAT * sizeof(int);  // 3.69 MB
    int*   hist = (int*)d_ws;
    float* sp   = (float*)((char*)d_ws + hist_bytes);                       // 96*196 f32

    hipMemsetAsync(hist, 0, hist_bytes, stream);
    k1_scores<<<NFRAME * TILES, 256, 0, stream>>>(x, gamma, beta, w_in, w1, w2, sp);
    k2_select<<<NFRAME * NSAMP / 4, 256, 0, stream>>>(sp, noise, hist);
    k3_output<<<NFRAME * 4, 256, 0, stream>>>(x, hist, out);
}

// Round 3
// 303.240 us; speedup vs baseline: 4.2264x; 1.4929x over previous
//
#include <hip/hip_runtime.h>
#include <math.h>

#define NFRAME 96
#define NTOK   197
#define NSPAT  196
#define DIM    512
#define DH     256
#define NSAMP  256
#define KSEL   49
#define SIG    0.05f
#define MPAD   208                 // 13*16 rows per frame (padded)
#define MTOT   (NFRAME * MPAD)     // 19968 = 156*128

typedef unsigned short u16;
typedef __attribute__((ext_vector_type(8))) short bf16x8;   // 8 bf16 (4 VGPRs)
typedef __attribute__((ext_vector_type(4))) float f32x4;

__device__ __forceinline__ float gelu_exact(float v) {
    return 0.5f * v * (1.0f + erff(v * 0.70710678118654752440f));
}
__device__ __forceinline__ unsigned bf16_rne(float f) {
    unsigned u = __float_as_uint(f);
    return (u + 0x7fffu + ((u >> 16) & 1u)) >> 16;
}
__device__ __forceinline__ float bf16_to_f(unsigned h) {
    return __uint_as_float(h << 16);
}

// ---------------------------------------------------------------------------
// K0a: transpose + hi/lo-split w_in and w1 -> wT[n][k] bf16 pairs. grid=512.
// ---------------------------------------------------------------------------
__global__ __launch_bounds__(256) void k0_wsplit(
    const float* __restrict__ w_in, const float* __restrict__ w1,
    u16* __restrict__ wiT_hi, u16* __restrict__ wiT_lo,
    u16* __restrict__ w1T_hi, u16* __restrict__ w1T_lo)
{
    const int n = blockIdx.x & 255, which = blockIdx.x >> 8;
    const float* w = which ? w1 : w_in;
    u16* th = which ? w1T_hi : wiT_hi;
    u16* tl = which ? w1T_lo : wiT_lo;
    for (int k = threadIdx.x; k < DIM; k += 256) {
        float v = w[(size_t)k * DH + n];
        unsigned hi = bf16_rne(v);
        unsigned lo = bf16_rne(v - bf16_to_f(hi));
        th[(size_t)n * DIM + k] = (u16)hi;
        tl[(size_t)n * DIM + k] = (u16)lo;
    }
}

// ---------------------------------------------------------------------------
// K0b: LN stats per padded row. grid = MTOT/4, one wave per row.
// ---------------------------------------------------------------------------
__global__ __launch_bounds__(256) void k0_stats(
    const float* __restrict__ x, float* __restrict__ mu_a, float* __restrict__ rs_a)
{
    const int row  = blockIdx.x * 4 + (threadIdx.x >> 6);
    const int lane = threadIdx.x & 63;
    const int f = row / MPAD;
    int rr = row - f * MPAD; if (rr > NTOK - 1) rr = NTOK - 1;   // clamp pad rows
    const float* xr = x + ((size_t)f * NTOK + rr) * DIM + lane * 8;
    float4 a = *(const float4*)xr, b = *(const float4*)(xr + 4);
    float s  = a.x + a.y + a.z + a.w + b.x + b.y + b.z + b.w;
    float sq = a.x*a.x + a.y*a.y + a.z*a.z + a.w*a.w +
               b.x*b.x + b.y*b.y + b.z*b.z + b.w*b.w;
    #pragma unroll
    for (int o = 32; o > 0; o >>= 1) {
        s  += __shfl_xor(s,  o, 64);
        sq += __shfl_xor(sq, o, 64);
    }
    if (lane == 0) {
        float mu  = s * (1.f / 512.f);
        float var = sq * (1.f / 512.f) - mu * mu;
        mu_a[row] = mu;
        rs_a[row] = 1.f / sqrtf(var + 1e-5f);
    }
}

// ---------------------------------------------------------------------------
// K1a: h = gelu(LN(x) @ w_in) via 3-term bf16-split MFMA.
// M=19968, N=256, K=512. Block = 128x128 tile, 4 waves, 64x64/wave.
// LN applied during A-staging. Output h stored as bf16 hi/lo.
// ---------------------------------------------------------------------------
#define LDA1 72
__global__ __launch_bounds__(256, 2) void k1_gemm1(
    const float* __restrict__ x, const float* __restrict__ gamma,
    const float* __restrict__ beta, const float* __restrict__ mu_a,
    const float* __restrict__ rs_a,
    const u16* __restrict__ wiT_hi, const u16* __restrict__ wiT_lo,
    u16* __restrict__ h_hi, u16* __restrict__ h_lo)
{
    __shared__ u16 Ah[128][LDA1], Al[128][LDA1], Bh[128][LDA1], Bl[128][LDA1];
    const int t = threadIdx.x, lane = t & 63, wv = t >> 6;
    const int Mb = blockIdx.x >> 1, Nb = blockIdx.x & 1;
    const int R0 = Mb * 128, N0 = Nb * 128;
    const int wr0 = (wv >> 1) * 64, wc0 = (wv & 1) * 64;
    const int m15 = lane & 15, q = lane >> 4;

    f32x4 acc[4][4];
    #pragma unroll
    for (int i = 0; i < 4; ++i)
        #pragma unroll
        for (int j = 0; j < 4; ++j)
            acc[i][j] = (f32x4){0.f, 0.f, 0.f, 0.f};

    // staging indices: 2 threads per row, 32 k's each
    const int sr = t >> 1, sh = t & 1;
    const int grow = R0 + sr;
    const int f_s = grow / MPAD;
    int rr_s = grow - f_s * MPAD; if (rr_s > NTOK - 1) rr_s = NTOK - 1;
    const float* xr = x + ((size_t)f_s * NTOK + rr_s) * DIM;
    const float mu = mu_a[grow], rs = rs_a[grow];
    const u16* bph = wiT_hi + (size_t)(N0 + sr) * DIM;
    const u16* bpl = wiT_lo + (size_t)(N0 + sr) * DIM;

    for (int k0 = 0; k0 < DIM; k0 += 64) {
        __syncthreads();
        // ---- stage A (LN + hi/lo split) ----
        #pragma unroll
        for (int g = 0; g < 4; ++g) {
            const int kk = g * 8;
            const int gc = k0 + sh * 32 + kk;
            float4 va = *(const float4*)(xr + gc);
            float4 vb = *(const float4*)(xr + gc + 4);
            float4 ga = *(const float4*)(gamma + gc);
            float4 gb = *(const float4*)(gamma + gc + 4);
            float4 ba = *(const float4*)(beta + gc);
            float4 bb = *(const float4*)(beta + gc + 4);
            float e[8]  = {va.x, va.y, va.z, va.w, vb.x, vb.y, vb.z, vb.w};
            float gg[8] = {ga.x, ga.y, ga.z, ga.w, gb.x, gb.y, gb.z, gb.w};
            float bt[8] = {ba.x, ba.y, ba.z, ba.w, bb.x, bb.y, bb.z, bb.w};
            unsigned hw[4], lw[4];
            #pragma unroll
            for (int p = 0; p < 4; ++p) {
                float s0 = rs * gg[2*p],   s1 = rs * gg[2*p+1];
                float v0 = e[2*p]   * s0 + (bt[2*p]   - mu * s0);
                float v1 = e[2*p+1] * s1 + (bt[2*p+1] - mu * s1);
                unsigned h0 = bf16_rne(v0), h1 = bf16_rne(v1);
                float l0 = v0 - bf16_to_f(h0), l1 = v1 - bf16_to_f(h1);
                hw[p] = h0 | (h1 << 16);
                lw[p] = bf16_rne(l0) | (bf16_rne(l1) << 16);
            }
            *(uint4*)&Ah[sr][sh*32 + kk] = make_uint4(hw[0], hw[1], hw[2], hw[3]);
            *(uint4*)&Al[sr][sh*32 + kk] = make_uint4(lw[0], lw[1], lw[2], lw[3]);
        }
        // ---- stage B (pure copy from pre-split wT) ----
        {
            const int kb = k0 + sh * 32;
            uint4 q0 = *(const uint4*)(bph + kb);
            uint4 q1 = *(const uint4*)(bph + kb + 8);
            uint4 q2 = *(const uint4*)(bph + kb + 16);
            uint4 q3 = *(const uint4*)(bph + kb + 24);
            *(uint4*)&Bh[sr][sh*32 + 0]  = q0;
            *(uint4*)&Bh[sr][sh*32 + 8]  = q1;
            *(uint4*)&Bh[sr][sh*32 + 16] = q2;
            *(uint4*)&Bh[sr][sh*32 + 24] = q3;
            uint4 r0 = *(const uint4*)(bpl + kb);
            uint4 r1 = *(const uint4*)(bpl + kb + 8);
            uint4 r2 = *(const uint4*)(bpl + kb + 16);
            uint4 r3 = *(const uint4*)(bpl + kb + 24);
            *(uint4*)&Bl[sr][sh*32 + 0]  = r0;
            *(uint4*)&Bl[sr][sh*32 + 8]  = r1;
            *(uint4*)&Bl[sr][sh*32 + 16] = r2;
            *(uint4*)&Bl[sr][sh*32 + 24] = r3;
        }
        __syncthreads();
        // ---- MFMA ----
        #pragma unroll
        for (int ks = 0; ks < 2; ++ks) {
            const int ko = ks * 32 + q * 8;
            bf16x8 a_h[4], a_l[4], b_h[4], b_l[4];
            #pragma unroll
            for (int i = 0; i < 4; ++i) {
                a_h[i] = *(const bf16x8*)&Ah[wr0 + i*16 + m15][ko];
                a_l[i] = *(const bf16x8*)&Al[wr0 + i*16 + m15][ko];
                b_h[i] = *(const bf16x8*)&Bh[wc0 + i*16 + m15][ko];
                b_l[i] = *(const bf16x8*)&Bl[wc0 + i*16 + m15][ko];
            }
            #pragma unroll
            for (int mt = 0; mt < 4; ++mt)
                #pragma unroll
                for (int nt = 0; nt < 4; ++nt) {
                    f32x4 c = acc[mt][nt];
                    c = __builtin_amdgcn_mfma_f32_16x16x32_bf16(a_h[mt], b_h[nt], c, 0, 0, 0);
                    c = __builtin_amdgcn_mfma_f32_16x16x32_bf16(a_l[mt], b_h[nt], c, 0, 0, 0);
                    c = __builtin_amdgcn_mfma_f32_16x16x32_bf16(a_h[mt], b_l[nt], c, 0, 0, 0);
                    acc[mt][nt] = c;
                }
        }
    }

    // ---- epilogue: gelu + split + store h ----
    #pragma unroll
    for (int mt = 0; mt < 4; ++mt)
        #pragma unroll
        for (int nt = 0; nt < 4; ++nt)
            #pragma unroll
            for (int reg = 0; reg < 4; ++reg) {
                int r = R0 + wr0 + mt*16 + q*4 + reg;
                int c = N0 + wc0 + nt*16 + m15;
                float v = gelu_exact(acc[mt][nt][reg]);
                unsigned hb = bf16_rne(v);
                unsigned lb = bf16_rne(v - bf16_to_f(hb));
                size_t off = (size_t)r * DH + c;
                h_hi[off] = (u16)hb;
                h_lo[off] = (u16)lb;
            }
}

// ---------------------------------------------------------------------------
// K1b: s2 = [h|g] @ w1; score = tanh(gelu(s2)@w2) fused in epilogue.
// Block = 64 rows x 256 cols (full N), 4 waves, 64x64/wave. BK=32.
// ---------------------------------------------------------------------------
#define LDB2 40
__global__ __launch_bounds__(256, 2) void k1_gemm2(
    const u16* __restrict__ h_hi, const u16* __restrict__ h_lo,
    const u16* __restrict__ w1T_hi, const u16* __restrict__ w1T_lo,
    const float* __restrict__ w2, float* __restrict__ sp)
{
    __shared__ u16 Ah[64][LDB2], Al[64][LDB2], Bh[256][LDB2], Bl[256][LDB2];
    __shared__ float red[4][64];
    const int t = threadIdx.x, lane = t & 63, wv = t >> 6;
    const int R0 = blockIdx.x * 64;
    const int wc0 = wv * 64;
    const int m15 = lane & 15, q = lane >> 4;

    f32x4 acc[4][4];
    #pragma unroll
    for (int i = 0; i < 4; ++i)
        #pragma unroll
        for (int j = 0; j < 4; ++j)
            acc[i][j] = (f32x4){0.f, 0.f, 0.f, 0.f};

    const int ar = t >> 2, aseg = (t & 3) * 8;
    const int agrow = R0 + ar;
    const size_t arow_off = (size_t)agrow * DH;
    const size_t g0_off   = (size_t)((agrow / MPAD) * MPAD) * DH;  // frame's row-0 h
    const u16* b_h = w1T_hi + (size_t)t * DIM;
    const u16* b_l = w1T_lo + (size_t)t * DIM;

    for (int k0 = 0; k0 < DIM; k0 += 32) {
        __syncthreads();
        // ---- stage A: h cols (k<256) or g cols (k>=256) ----
        {
            size_t src = (k0 < DH) ? (arow_off + k0 + aseg)
                                   : (g0_off + (k0 - DH) + aseg);
            *(uint4*)&Ah[ar][aseg] = *(const uint4*)(h_hi + src);
            *(uint4*)&Al[ar][aseg] = *(const uint4*)(h_lo + src);
        }
        // ---- stage B ----
        {
            const u16* ph = b_h + k0; const u16* pl = b_l + k0;
            uint4 q0 = *(const uint4*)(ph);      uint4 q1 = *(const uint4*)(ph + 8);
            uint4 q2 = *(const uint4*)(ph + 16); uint4 q3 = *(const uint4*)(ph + 24);
            *(uint4*)&Bh[t][0]  = q0; *(uint4*)&Bh[t][8]  = q1;
            *(uint4*)&Bh[t][16] = q2; *(uint4*)&Bh[t][24] = q3;
            uint4 r0 = *(const uint4*)(pl);      uint4 r1 = *(const uint4*)(pl + 8);
            uint4 r2 = *(const uint4*)(pl + 16); uint4 r3 = *(const uint4*)(pl + 24);
            *(uint4*)&Bl[t][0]  = r0; *(uint4*)&Bl[t][8]  = r1;
            *(uint4*)&Bl[t][16] = r2; *(uint4*)&Bl[t][24] = r3;
        }
        __syncthreads();
        // ---- MFMA ----
        {
            const int ko = q * 8;
            bf16x8 a_h[4], a_l[4], bb_h[4], bb_l[4];
            #pragma unroll
            for (int i = 0; i < 4; ++i) {
                a_h[i]  = *(const bf16x8*)&Ah[i*16 + m15][ko];
                a_l[i]  = *(const bf16x8*)&Al[i*16 + m15][ko];
                bb_h[i] = *(const bf16x8*)&Bh[wc0 + i*16 + m15][ko];
                bb_l[i] = *(const bf16x8*)&Bl[wc0 + i*16 + m15][ko];
            }
            #pragma unroll
            for (int mt = 0; mt < 4; ++mt)
                #pragma unroll
                for (int nt = 0; nt < 4; ++nt) {
                    f32x4 c = acc[mt][nt];
                    c = __builtin_amdgcn_mfma_f32_16x16x32_bf16(a_h[mt], bb_h[nt], c, 0, 0, 0);
                    c = __builtin_amdgcn_mfma_f32_16x16x32_bf16(a_l[mt], bb_h[nt], c, 0, 0, 0);
                    c = __builtin_amdgcn_mfma_f32_16x16x32_bf16(a_h[mt], bb_l[nt], c, 0, 0, 0);
                    acc[mt][nt] = c;
                }
        }
    }

    // ---- epilogue: gelu -> .w2 -> cross-lane & cross-wave reduce -> tanh ----
    float w2v[4];
    #pragma unroll
    for (int nt = 0; nt < 4; ++nt) w2v[nt] = w2[wc0 + nt*16 + m15];
    float pr[4][4];
    #pragma unroll
    for (int mt = 0; mt < 4; ++mt)
        #pragma unroll
        for (int reg = 0; reg < 4; ++reg) {
            float s = 0.f;
            #pragma unroll
            for (int nt = 0; nt < 4; ++nt)
                s += gelu_exact(acc[mt][nt][reg]) * w2v[nt];
            #pragma unroll
            for (int o = 1; o <= 8; o <<= 1)
                s += __shfl_xor(s, o, 64);
            pr[mt][reg] = s;
        }
    if (m15 == 0) {
        #pragma unroll
        for (int mt = 0; mt < 4; ++mt)
            #pragma unroll
            for (int reg = 0; reg < 4; ++reg)
                red[wv][mt*16 + q*4 + reg] = pr[mt][reg];
    }
    __syncthreads();
    if (t < 64) {
        float s = red[0][t] + red[1][t] + red[2][t] + red[3][t];
        int grow = R0 + t;
        int f = grow / MPAD;
        int rr = grow - f * MPAD;
        if (rr >= 1 && rr <= NSPAT)
            sp[f * NSPAT + rr - 1] = tanhf(s);
    }
}

// ---------------------------------------------------------------------------
// K2: per-sample top-49 via radix descent + rank histogram (unchanged).
// ---------------------------------------------------------------------------
__global__ __launch_bounds__(256) void k2_select(
    const float* __restrict__ sp, const float* __restrict__ noise,
    int* __restrict__ hist)
{
    const int wid  = blockIdx.x * 4 + (threadIdx.x >> 6);
    const int lane = threadIdx.x & 63;
    const int b    = wid >> 8;
    const float* nz  = noise + (size_t)wid * NSPAT;
    const float* spb = sp + (size_t)b * NSPAT;

    unsigned key[4];
    #pragma unroll
    for (int j = 0; j < 4; ++j) {
        int l = lane + 64 * j;
        if (l < NSPAT) {
            float p = spb[l] + nz[l] * SIG;
            unsigned u = __float_as_uint(p);
            key[j] = (u & 0x80000000u) ? ~u : (u | 0x80000000u);
        } else {
            key[j] = 0u;
        }
    }

    unsigned ans = 0u;
    for (int bit = 31; bit >= 0; --bit) {
        unsigned cand = ans | (1u << bit);
        int cnt = 0;
        #pragma unroll
        for (int j = 0; j < 4; ++j)
            cnt += __popcll(__ballot(key[j] >= cand));
        if (cnt >= KSEL) ans = cand;
    }

    const unsigned long long lmask = (1ull << lane) - 1ull;
    unsigned long long eq[4];
    int cgt = 0;
    #pragma unroll
    for (int j = 0; j < 4; ++j) {
        cgt += __popcll(__ballot(key[j] > ans));
        eq[j] = __ballot(key[j] == ans);
    }
    const int quota = KSEL - cgt;

    int eqpre[4]; { int run = 0;
        #pragma unroll
        for (int j = 0; j < 4; ++j) { eqpre[j] = run; run += __popcll(eq[j]); } }

    bool selj[4];
    #pragma unroll
    for (int j = 0; j < 4; ++j) {
        bool iseq = (key[j] == ans);
        int trk = eqpre[j] + __popcll(eq[j] & lmask);
        selj[j] = (key[j] > ans) || (iseq && trk < quota);
    }

    int pre = 0;
    #pragma unroll
    for (int j = 0; j < 4; ++j) {
        unsigned long long sb = __ballot(selj[j]);
        int rk = pre + __popcll(sb & lmask);
        if (selj[j])
            atomicAdd(&hist[((size_t)b * KSEL + rk) * NSPAT + lane + 64 * j], 1);
        pre += __popcll(sb);
    }
}

// ---------------------------------------------------------------------------
// K3: out = [cls | (hist/256) @ spat] (unchanged from round 2).
// ---------------------------------------------------------------------------
__global__ __launch_bounds__(256) void k3_output(
    const float* __restrict__ x, const int* __restrict__ hist,
    float* __restrict__ out)
{
    const int b  = blockIdx.x >> 2;
    const int ds = blockIdx.x & 3;
    const int d0 = ds * 128;
    const int t  = threadIdx.x;
    const int tdc = t & 31;
    const int tk  = t >> 5;

    __shared__ float hist_s[NSPAT * KSEL + 8];

    const int* hb = hist + (size_t)b * KSEL * NSPAT;
    for (int i = t; i < KSEL * NSPAT; i += 256) {
        int k = i / NSPAT;
        int l = i - k * NSPAT;
        hist_s[l * KSEL + k] = (float)hb[i];
    }
    if (t < 128)
        out[(size_t)b * 50 * DIM + d0 + t] = x[(size_t)b * NTOK * DIM + d0 + t];
    __syncthreads();

    const float* xs = x + ((size_t)b * NTOK + 1) * DIM + d0 + tdc * 4;
    float4 acc[7];
    #pragma unroll
    for (int i = 0; i < 7; ++i) acc[i] = make_float4(0.f, 0.f, 0.f, 0.f);

    #pragma unroll 2
    for (int l = 0; l < NSPAT; ++l) {
        float4 v = *(const float4*)(xs + (size_t)l * DIM);
        const float* hl = &hist_s[l * KSEL + tk];
        #pragma unroll
        for (int i = 0; i < 7; ++i) {
            float w = hl[8 * i];
            acc[i].x += w * v.x; acc[i].y += w * v.y;
            acc[i].z += w * v.z; acc[i].w += w * v.w;
        }
    }

    const float inv = 1.f / 256.f;
    #pragma unroll
    for (int i = 0; i < 7; ++i) {
        int k = tk + 8 * i;
        if (k < KSEL) {
            float4 o = make_float4(acc[i].x * inv, acc[i].y * inv,
                                   acc[i].z * inv, acc[i].w * inv);
            *(float4*)&out[((size_t)b * 50 + 1 + k) * DIM + d0 + tdc * 4] = o;
        }
    }
}

// ---------------------------------------------------------------------------
extern "C" void kernel_launch(void* const* d_in, const int* in_sizes, int n_in,
                              void* d_out, int out_size, void* d_ws, size_t ws_size,
                              hipStream_t stream)
{
    const float* x     = (const float*)d_in[0];
    const float* noise = (const float*)d_in[1];
    const float* gamma = (const float*)d_in[2];
    const float* beta  = (const float*)d_in[3];
    const float* w_in  = (const float*)d_in[4];
    const float* w1    = (const float*)d_in[5];
    const float* w2    = (const float*)d_in[6];
    float* out = (float*)d_out;

    // ws layout (bytes, all 256-aligned; total ~25.4 MB)
    char* ws = (char*)d_ws;
    int*   hist    = (int*)  (ws + 0);           // 96*49*196*4 = 3,687,936
    float* sp      = (float*)(ws + 3687936);     // 96*196*4    =    75,264
    float* mu_a    = (float*)(ws + 3763200);     // 19968*4     =    79,872
    float* rs_a    = (float*)(ws + 3843072);     // 19968*4     =    79,872
    u16*   wiT_hi  = (u16*)  (ws + 3922944);     // 256*512*2   =   262,144
    u16*   wiT_lo  = (u16*)  (ws + 4185088);
    u16*   w1T_hi  = (u16*)  (ws + 4447232);
    u16*   w1T_lo  = (u16*)  (ws + 4709376);
    u16*   h_hi    = (u16*)  (ws + 4971520);     // 19968*256*2 = 10,223,616
    u16*   h_lo    = (u16*)  (ws + 15195136);    // end 25,418,752

    hipMemsetAsync(hist, 0, (size_t)NFRAME * KSEL * NSPAT * sizeof(int), stream);
    k0_wsplit<<<512, 256, 0, stream>>>(w_in, w1, wiT_hi, wiT_lo, w1T_hi, w1T_lo);
    k0_stats<<<MTOT / 4, 256, 0, stream>>>(x, mu_a, rs_a);
    k1_gemm1<<<(MTOT / 128) * 2, 256, 0, stream>>>(x, gamma, beta, mu_a, rs_a,
                                                   wiT_hi, wiT_lo, h_hi, h_lo);
    k1_gemm2<<<MTOT / 64, 256, 0, stream>>>(h_hi, h_lo, w1T_hi, w1T_lo, w2, sp);
    k2_select<<<NFRAME * NSAMP / 4, 256, 0, stream>>>(sp, noise, hist);
    k3_output<<<NFRAME * 4, 256, 0, stream>>>(x, hist, out);
}

// Round 4
// 264.387 us; speedup vs baseline: 4.8475x; 1.1470x over previous
//
#include <hip/hip_runtime.h>
#include <math.h>

#define NFRAME 96
#define NTOK   197
#define NSPAT  196
#define DIM    512
#define DH     256
#define NSAMP  256
#define KSEL   49
#define SIG    0.05f
#define MPAD   208                 // 13*16 rows per frame (padded)
#define MTOT   (NFRAME * MPAD)     // 19968 = 156*128

typedef unsigned short u16;
typedef __attribute__((ext_vector_type(8))) short bf16x8;   // 8 bf16 (4 VGPRs)
typedef __attribute__((ext_vector_type(4))) float f32x4;

__device__ __forceinline__ float gelu_exact(float v) {
    return 0.5f * v * (1.0f + erff(v * 0.70710678118654752440f));
}
__device__ __forceinline__ unsigned bf16_rne(float f) {
    unsigned u = __float_as_uint(f);
    return (u + 0x7fffu + ((u >> 16) & 1u)) >> 16;
}
__device__ __forceinline__ float bf16_to_f(unsigned h) {
    return __uint_as_float(h << 16);
}

// ---------------------------------------------------------------------------
// K0a: transpose + hi/lo-split w_in and w1 -> wT[n][k] bf16 pairs. grid=512.
// ---------------------------------------------------------------------------
__global__ __launch_bounds__(256) void k0_wsplit(
    const float* __restrict__ w_in, const float* __restrict__ w1,
    u16* __restrict__ wiT_hi, u16* __restrict__ wiT_lo,
    u16* __restrict__ w1T_hi, u16* __restrict__ w1T_lo)
{
    const int n = blockIdx.x & 255, which = blockIdx.x >> 8;
    const float* w = which ? w1 : w_in;
    u16* th = which ? w1T_hi : wiT_hi;
    u16* tl = which ? w1T_lo : wiT_lo;
    for (int k = threadIdx.x; k < DIM; k += 256) {
        float v = w[(size_t)k * DH + n];
        unsigned hi = bf16_rne(v);
        unsigned lo = bf16_rne(v - bf16_to_f(hi));
        th[(size_t)n * DIM + k] = (u16)hi;
        tl[(size_t)n * DIM + k] = (u16)lo;
    }
}

// ---------------------------------------------------------------------------
// K0b: LN stats per padded row. grid = MTOT/4, one wave per row.
// ---------------------------------------------------------------------------
__global__ __launch_bounds__(256) void k0_stats(
    const float* __restrict__ x, float* __restrict__ mu_a, float* __restrict__ rs_a)
{
    const int row  = blockIdx.x * 4 + (threadIdx.x >> 6);
    const int lane = threadIdx.x & 63;
    const int f = row / MPAD;
    int rr = row - f * MPAD; if (rr > NTOK - 1) rr = NTOK - 1;   // clamp pad rows
    const float* xr = x + ((size_t)f * NTOK + rr) * DIM + lane * 8;
    float4 a = *(const float4*)xr, b = *(const float4*)(xr + 4);
    float s  = a.x + a.y + a.z + a.w + b.x + b.y + b.z + b.w;
    float sq = a.x*a.x + a.y*a.y + a.z*a.z + a.w*a.w +
               b.x*b.x + b.y*b.y + b.z*b.z + b.w*b.w;
    #pragma unroll
    for (int o = 32; o > 0; o >>= 1) {
        s  += __shfl_xor(s,  o, 64);
        sq += __shfl_xor(sq, o, 64);
    }
    if (lane == 0) {
        float mu  = s * (1.f / 512.f);
        float var = sq * (1.f / 512.f) - mu * mu;
        mu_a[row] = mu;
        rs_a[row] = 1.f / sqrtf(var + 1e-5f);
    }
}

// ---------------------------------------------------------------------------
// K1a: h = gelu(LN(x) @ w_in) via 3-term bf16-split MFMA.
// M=19968, N=256, K=512. Block = 128x128 tile, 4 waves, 64x64/wave.
// ---------------------------------------------------------------------------
#define LDA1 72
__global__ __launch_bounds__(256, 2) void k1_gemm1(
    const float* __restrict__ x, const float* __restrict__ gamma,
    const float* __restrict__ beta, const float* __restrict__ mu_a,
    const float* __restrict__ rs_a,
    const u16* __restrict__ wiT_hi, const u16* __restrict__ wiT_lo,
    u16* __restrict__ h_hi, u16* __restrict__ h_lo)
{
    __shared__ u16 Ah[128][LDA1], Al[128][LDA1], Bh[128][LDA1], Bl[128][LDA1];
    const int t = threadIdx.x, lane = t & 63, wv = t >> 6;
    const int Mb = blockIdx.x >> 1, Nb = blockIdx.x & 1;
    const int R0 = Mb * 128, N0 = Nb * 128;
    const int wr0 = (wv >> 1) * 64, wc0 = (wv & 1) * 64;
    const int m15 = lane & 15, q = lane >> 4;

    f32x4 acc[4][4];
    #pragma unroll
    for (int i = 0; i < 4; ++i)
        #pragma unroll
        for (int j = 0; j < 4; ++j)
            acc[i][j] = (f32x4){0.f, 0.f, 0.f, 0.f};

    const int sr = t >> 1, sh = t & 1;
    const int grow = R0 + sr;
    const int f_s = grow / MPAD;
    int rr_s = grow - f_s * MPAD; if (rr_s > NTOK - 1) rr_s = NTOK - 1;
    const float* xr = x + ((size_t)f_s * NTOK + rr_s) * DIM;
    const float mu = mu_a[grow], rs = rs_a[grow];
    const u16* bph = wiT_hi + (size_t)(N0 + sr) * DIM;
    const u16* bpl = wiT_lo + (size_t)(N0 + sr) * DIM;

    for (int k0 = 0; k0 < DIM; k0 += 64) {
        __syncthreads();
        // ---- stage A (LN + hi/lo split) ----
        #pragma unroll
        for (int g = 0; g < 4; ++g) {
            const int kk = g * 8;
            const int gc = k0 + sh * 32 + kk;
            float4 va = *(const float4*)(xr + gc);
            float4 vb = *(const float4*)(xr + gc + 4);
            float4 ga = *(const float4*)(gamma + gc);
            float4 gb = *(const float4*)(gamma + gc + 4);
            float4 ba = *(const float4*)(beta + gc);
            float4 bb = *(const float4*)(beta + gc + 4);
            float e[8]  = {va.x, va.y, va.z, va.w, vb.x, vb.y, vb.z, vb.w};
            float gg[8] = {ga.x, ga.y, ga.z, ga.w, gb.x, gb.y, gb.z, gb.w};
            float bt[8] = {ba.x, ba.y, ba.z, ba.w, bb.x, bb.y, bb.z, bb.w};
            unsigned hw[4], lw[4];
            #pragma unroll
            for (int p = 0; p < 4; ++p) {
                float s0 = rs * gg[2*p],   s1 = rs * gg[2*p+1];
                float v0 = e[2*p]   * s0 + (bt[2*p]   - mu * s0);
                float v1 = e[2*p+1] * s1 + (bt[2*p+1] - mu * s1);
                unsigned h0 = bf16_rne(v0), h1 = bf16_rne(v1);
                float l0 = v0 - bf16_to_f(h0), l1 = v1 - bf16_to_f(h1);
                hw[p] = h0 | (h1 << 16);
                lw[p] = bf16_rne(l0) | (bf16_rne(l1) << 16);
            }
            *(uint4*)&Ah[sr][sh*32 + kk] = make_uint4(hw[0], hw[1], hw[2], hw[3]);
            *(uint4*)&Al[sr][sh*32 + kk] = make_uint4(lw[0], lw[1], lw[2], lw[3]);
        }
        // ---- stage B (pure copy from pre-split wT) ----
        {
            const int kb = k0 + sh * 32;
            uint4 q0 = *(const uint4*)(bph + kb);
            uint4 q1 = *(const uint4*)(bph + kb + 8);
            uint4 q2 = *(const uint4*)(bph + kb + 16);
            uint4 q3 = *(const uint4*)(bph + kb + 24);
            *(uint4*)&Bh[sr][sh*32 + 0]  = q0;
            *(uint4*)&Bh[sr][sh*32 + 8]  = q1;
            *(uint4*)&Bh[sr][sh*32 + 16] = q2;
            *(uint4*)&Bh[sr][sh*32 + 24] = q3;
            uint4 r0 = *(const uint4*)(bpl + kb);
            uint4 r1 = *(const uint4*)(bpl + kb + 8);
            uint4 r2 = *(const uint4*)(bpl + kb + 16);
            uint4 r3 = *(const uint4*)(bpl + kb + 24);
            *(uint4*)&Bl[sr][sh*32 + 0]  = r0;
            *(uint4*)&Bl[sr][sh*32 + 8]  = r1;
            *(uint4*)&Bl[sr][sh*32 + 16] = r2;
            *(uint4*)&Bl[sr][sh*32 + 24] = r3;
        }
        __syncthreads();
        // ---- MFMA ----
        #pragma unroll
        for (int ks = 0; ks < 2; ++ks) {
            const int ko = ks * 32 + q * 8;
            bf16x8 a_h[4], a_l[4], b_h[4], b_l[4];
            #pragma unroll
            for (int i = 0; i < 4; ++i) {
                a_h[i] = *(const bf16x8*)&Ah[wr0 + i*16 + m15][ko];
                a_l[i] = *(const bf16x8*)&Al[wr0 + i*16 + m15][ko];
                b_h[i] = *(const bf16x8*)&Bh[wc0 + i*16 + m15][ko];
                b_l[i] = *(const bf16x8*)&Bl[wc0 + i*16 + m15][ko];
            }
            #pragma unroll
            for (int mt = 0; mt < 4; ++mt)
                #pragma unroll
                for (int nt = 0; nt < 4; ++nt) {
                    f32x4 c = acc[mt][nt];
                    c = __builtin_amdgcn_mfma_f32_16x16x32_bf16(a_h[mt], b_h[nt], c, 0, 0, 0);
                    c = __builtin_amdgcn_mfma_f32_16x16x32_bf16(a_l[mt], b_h[nt], c, 0, 0, 0);
                    c = __builtin_amdgcn_mfma_f32_16x16x32_bf16(a_h[mt], b_l[nt], c, 0, 0, 0);
                    acc[mt][nt] = c;
                }
        }
    }

    #pragma unroll
    for (int mt = 0; mt < 4; ++mt)
        #pragma unroll
        for (int nt = 0; nt < 4; ++nt)
            #pragma unroll
            for (int reg = 0; reg < 4; ++reg) {
                int r = R0 + wr0 + mt*16 + q*4 + reg;
                int c = N0 + wc0 + nt*16 + m15;
                float v = gelu_exact(acc[mt][nt][reg]);
                unsigned hb = bf16_rne(v);
                unsigned lb = bf16_rne(v - bf16_to_f(hb));
                size_t off = (size_t)r * DH + c;
                h_hi[off] = (u16)hb;
                h_lo[off] = (u16)lb;
            }
}

// ---------------------------------------------------------------------------
// K1b: s2 = [h|g] @ w1; score = tanh(gelu(s2)@w2) fused in epilogue.
// ---------------------------------------------------------------------------
#define LDB2 40
__global__ __launch_bounds__(256, 2) void k1_gemm2(
    const u16* __restrict__ h_hi, const u16* __restrict__ h_lo,
    const u16* __restrict__ w1T_hi, const u16* __restrict__ w1T_lo,
    const float* __restrict__ w2, float* __restrict__ sp)
{
    __shared__ u16 Ah[64][LDB2], Al[64][LDB2], Bh[256][LDB2], Bl[256][LDB2];
    __shared__ float red[4][64];
    const int t = threadIdx.x, lane = t & 63, wv = t >> 6;
    const int R0 = blockIdx.x * 64;
    const int wc0 = wv * 64;
    const int m15 = lane & 15, q = lane >> 4;

    f32x4 acc[4][4];
    #pragma unroll
    for (int i = 0; i < 4; ++i)
        #pragma unroll
        for (int j = 0; j < 4; ++j)
            acc[i][j] = (f32x4){0.f, 0.f, 0.f, 0.f};

    const int ar = t >> 2, aseg = (t & 3) * 8;
    const int agrow = R0 + ar;
    const size_t arow_off = (size_t)agrow * DH;
    const size_t g0_off   = (size_t)((agrow / MPAD) * MPAD) * DH;
    const u16* b_h = w1T_hi + (size_t)t * DIM;
    const u16* b_l = w1T_lo + (size_t)t * DIM;

    for (int k0 = 0; k0 < DIM; k0 += 32) {
        __syncthreads();
        {
            size_t src = (k0 < DH) ? (arow_off + k0 + aseg)
                                   : (g0_off + (k0 - DH) + aseg);
            *(uint4*)&Ah[ar][aseg] = *(const uint4*)(h_hi + src);
            *(uint4*)&Al[ar][aseg] = *(const uint4*)(h_lo + src);
        }
        {
            const u16* ph = b_h + k0; const u16* pl = b_l + k0;
            uint4 q0 = *(const uint4*)(ph);      uint4 q1 = *(const uint4*)(ph + 8);
            uint4 q2 = *(const uint4*)(ph + 16); uint4 q3 = *(const uint4*)(ph + 24);
            *(uint4*)&Bh[t][0]  = q0; *(uint4*)&Bh[t][8]  = q1;
            *(uint4*)&Bh[t][16] = q2; *(uint4*)&Bh[t][24] = q3;
            uint4 r0 = *(const uint4*)(pl);      uint4 r1 = *(const uint4*)(pl + 8);
            uint4 r2 = *(const uint4*)(pl + 16); uint4 r3 = *(const uint4*)(pl + 24);
            *(uint4*)&Bl[t][0]  = r0; *(uint4*)&Bl[t][8]  = r1;
            *(uint4*)&Bl[t][16] = r2; *(uint4*)&Bl[t][24] = r3;
        }
        __syncthreads();
        {
            const int ko = q * 8;
            bf16x8 a_h[4], a_l[4], bb_h[4], bb_l[4];
            #pragma unroll
            for (int i = 0; i < 4; ++i) {
                a_h[i]  = *(const bf16x8*)&Ah[i*16 + m15][ko];
                a_l[i]  = *(const bf16x8*)&Al[i*16 + m15][ko];
                bb_h[i] = *(const bf16x8*)&Bh[wc0 + i*16 + m15][ko];
                bb_l[i] = *(const bf16x8*)&Bl[wc0 + i*16 + m15][ko];
            }
            #pragma unroll
            for (int mt = 0; mt < 4; ++mt)
                #pragma unroll
                for (int nt = 0; nt < 4; ++nt) {
                    f32x4 c = acc[mt][nt];
                    c = __builtin_amdgcn_mfma_f32_16x16x32_bf16(a_h[mt], bb_h[nt], c, 0, 0, 0);
                    c = __builtin_amdgcn_mfma_f32_16x16x32_bf16(a_l[mt], bb_h[nt], c, 0, 0, 0);
                    c = __builtin_amdgcn_mfma_f32_16x16x32_bf16(a_h[mt], bb_l[nt], c, 0, 0, 0);
                    acc[mt][nt] = c;
                }
        }
    }

    float w2v[4];
    #pragma unroll
    for (int nt = 0; nt < 4; ++nt) w2v[nt] = w2[wc0 + nt*16 + m15];
    float pr[4][4];
    #pragma unroll
    for (int mt = 0; mt < 4; ++mt)
        #pragma unroll
        for (int reg = 0; reg < 4; ++reg) {
            float s = 0.f;
            #pragma unroll
            for (int nt = 0; nt < 4; ++nt)
                s += gelu_exact(acc[mt][nt][reg]) * w2v[nt];
            #pragma unroll
            for (int o = 1; o <= 8; o <<= 1)
                s += __shfl_xor(s, o, 64);
            pr[mt][reg] = s;
        }
    if (m15 == 0) {
        #pragma unroll
        for (int mt = 0; mt < 4; ++mt)
            #pragma unroll
            for (int reg = 0; reg < 4; ++reg)
                red[wv][mt*16 + q*4 + reg] = pr[mt][reg];
    }
    __syncthreads();
    if (t < 64) {
        float s = red[0][t] + red[1][t] + red[2][t] + red[3][t];
        int grow = R0 + t;
        int f = grow / MPAD;
        int rr = grow - f * MPAD;
        if (rr >= 1 && rr <= NSPAT)
            sp[f * NSPAT + rr - 1] = tanhf(s);
    }
}

// ---------------------------------------------------------------------------
// K2: top-49 radix descent, LDS-accumulated histogram.
// grid = 192 (2 blocks/frame), block = 1024 (16 waves, 8 samples/wave).
// Flush: plain stores to a per-block hist copy (no global atomics).
// ---------------------------------------------------------------------------
__global__ __launch_bounds__(1024) void k2_select(
    const float* __restrict__ sp, const float* __restrict__ noise,
    int* __restrict__ hist2)
{
    const int fb   = blockIdx.x;         // 0..191
    const int f    = fb >> 1;
    const int half = fb & 1;
    const int t    = threadIdx.x;
    const int lane = t & 63;
    const int wv   = t >> 6;             // 0..15

    __shared__ int hist_s[KSEL * NSPAT];  // 38.4 KB
    for (int i = t; i < KSEL * NSPAT; i += 1024) hist_s[i] = 0;

    // per-frame scores, loaded once into registers (shared by all 8 samples)
    float spv[4];
    #pragma unroll
    for (int j = 0; j < 4; ++j) {
        int l = lane + 64 * j;
        spv[j] = (l < NSPAT) ? sp[f * NSPAT + l] : 0.f;
    }
    __syncthreads();

    const unsigned long long lmask = (1ull << lane) - 1ull;

    for (int si = 0; si < 8; ++si) {
        const int s = half * 128 + wv * 8 + si;
        const float* nz = noise + ((size_t)f * NSAMP + s) * NSPAT;
        unsigned key[4];
        #pragma unroll
        for (int j = 0; j < 4; ++j) {
            int l = lane + 64 * j;
            if (l < NSPAT) {
                float p = spv[j] + nz[l] * SIG;
                unsigned u = __float_as_uint(p);
                key[j] = (u & 0x80000000u) ? ~u : (u | 0x80000000u);
            } else {
                key[j] = 0u;
            }
        }

        unsigned ans = 0u;
        for (int bit = 31; bit >= 0; --bit) {
            unsigned cand = ans | (1u << bit);
            int cnt = 0;
            #pragma unroll
            for (int j = 0; j < 4; ++j)
                cnt += __popcll(__ballot(key[j] >= cand));
            if (cnt >= KSEL) ans = cand;
        }

        unsigned long long eq[4];
        int cgt = 0;
        #pragma unroll
        for (int j = 0; j < 4; ++j) {
            cgt += __popcll(__ballot(key[j] > ans));
            eq[j] = __ballot(key[j] == ans);
        }
        const int quota = KSEL - cgt;
        int eqpre[4]; { int run = 0;
            #pragma unroll
            for (int j = 0; j < 4; ++j) { eqpre[j] = run; run += __popcll(eq[j]); } }

        int pre = 0;
        #pragma unroll
        for (int j = 0; j < 4; ++j) {
            bool iseq = (key[j] == ans);
            int trk = eqpre[j] + __popcll(eq[j] & lmask);
            bool selj = (key[j] > ans) || (iseq && trk < quota);
            unsigned long long sb = __ballot(selj);
            int rk = pre + __popcll(sb & lmask);
            if (selj)
                atomicAdd(&hist_s[rk * NSPAT + lane + 64 * j], 1);
            pre += __popcll(sb);
        }
    }

    __syncthreads();
    int* hb = hist2 + (size_t)fb * (KSEL * NSPAT);
    for (int i = t; i < KSEL * NSPAT; i += 1024)
        hb[i] = hist_s[i];
}

// ---------------------------------------------------------------------------
// K3: out = [cls | (hist/256) @ spat]; sums the 2 per-half hist copies.
// ---------------------------------------------------------------------------
__global__ __launch_bounds__(256) void k3_output(
    const float* __restrict__ x, const int* __restrict__ hist2,
    float* __restrict__ out)
{
    const int b  = blockIdx.x >> 2;
    const int ds = blockIdx.x & 3;
    const int d0 = ds * 128;
    const int t  = threadIdx.x;
    const int tdc = t & 31;
    const int tk  = t >> 5;

    __shared__ float hist_s[NSPAT * KSEL + 8];

    const int* h0 = hist2 + (size_t)(2 * b) * (KSEL * NSPAT);
    const int* h1 = h0 + KSEL * NSPAT;
    for (int i = t; i < KSEL * NSPAT; i += 256) {
        int k = i / NSPAT;
        int l = i - k * NSPAT;
        hist_s[l * KSEL + k] = (float)(h0[i] + h1[i]);
    }
    if (t < 128)
        out[(size_t)b * 50 * DIM + d0 + t] = x[(size_t)b * NTOK * DIM + d0 + t];
    __syncthreads();

    const float* xs = x + ((size_t)b * NTOK + 1) * DIM + d0 + tdc * 4;
    float4 acc[7];
    #pragma unroll
    for (int i = 0; i < 7; ++i) acc[i] = make_float4(0.f, 0.f, 0.f, 0.f);

    #pragma unroll 2
    for (int l = 0; l < NSPAT; ++l) {
        float4 v = *(const float4*)(xs + (size_t)l * DIM);
        const float* hl = &hist_s[l * KSEL + tk];
        #pragma unroll
        for (int i = 0; i < 7; ++i) {
            float w = hl[8 * i];
            acc[i].x += w * v.x; acc[i].y += w * v.y;
            acc[i].z += w * v.z; acc[i].w += w * v.w;
        }
    }

    const float inv = 1.f / 256.f;
    #pragma unroll
    for (int i = 0; i < 7; ++i) {
        int k = tk + 8 * i;
        if (k < KSEL) {
            float4 o = make_float4(acc[i].x * inv, acc[i].y * inv,
                                   acc[i].z * inv, acc[i].w * inv);
            *(float4*)&out[((size_t)b * 50 + 1 + k) * DIM + d0 + tdc * 4] = o;
        }
    }
}

// ---------------------------------------------------------------------------
extern "C" void kernel_launch(void* const* d_in, const int* in_sizes, int n_in,
                              void* d_out, int out_size, void* d_ws, size_t ws_size,
                              hipStream_t stream)
{
    const float* x     = (const float*)d_in[0];
    const float* noise = (const float*)d_in[1];
    const float* gamma = (const float*)d_in[2];
    const float* beta  = (const float*)d_in[3];
    const float* w_in  = (const float*)d_in[4];
    const float* w1    = (const float*)d_in[5];
    const float* w2    = (const float*)d_in[6];
    float* out = (float*)d_out;

    // ws layout (bytes; total ~29.1 MB)
    char* ws = (char*)d_ws;
    int*   hist2   = (int*)  (ws + 0);           // 192*49*196*4 = 7,375,872
    float* sp      = (float*)(ws + 7375872);     // 75,264
    float* mu_a    = (float*)(ws + 7451136);     // 79,872
    float* rs_a    = (float*)(ws + 7531008);     // 79,872
    u16*   wiT_hi  = (u16*)  (ws + 7610880);     // 262,144
    u16*   wiT_lo  = (u16*)  (ws + 7873024);
    u16*   w1T_hi  = (u16*)  (ws + 8135168);
    u16*   w1T_lo  = (u16*)  (ws + 8397312);
    u16*   h_hi    = (u16*)  (ws + 8659456);     // 10,223,616
    u16*   h_lo    = (u16*)  (ws + 18883072);    // end 29,106,688

    k0_wsplit<<<512, 256, 0, stream>>>(w_in, w1, wiT_hi, wiT_lo, w1T_hi, w1T_lo);
    k0_stats<<<MTOT / 4, 256, 0, stream>>>(x, mu_a, rs_a);
    k1_gemm1<<<(MTOT / 128) * 2, 256, 0, stream>>>(x, gamma, beta, mu_a, rs_a,
                                                   wiT_hi, wiT_lo, h_hi, h_lo);
    k1_gemm2<<<MTOT / 64, 256, 0, stream>>>(h_hi, h_lo, w1T_hi, w1T_lo, w2, sp);
    k2_select<<<NFRAME * 2, 1024, 0, stream>>>(sp, noise, hist2);
    k3_output<<<NFRAME * 4, 256, 0, stream>>>(x, hist2, out);
}

// Round 5
// 247.999 us; speedup vs baseline: 5.1678x; 1.0661x over previous
//
#include <hip/hip_runtime.h>
#include <math.h>

#define NFRAME 96
#define NTOK   197
#define NSPAT  196
#define DIM    512
#define DH     256
#define NSAMP  256
#define KSEL   49
#define SIG    0.05f
#define MPAD   208                 // padded rows per frame
#define MTOT   (NFRAME * MPAD)     // 19968 = 156*128

typedef unsigned short u16;
typedef __attribute__((ext_vector_type(8))) short bf16x8;   // 8 bf16 (4 VGPRs)
typedef __attribute__((ext_vector_type(4))) float f32x4;

__device__ __forceinline__ float gelu_exact(float v) {
    return 0.5f * v * (1.0f + erff(v * 0.70710678118654752440f));
}
__device__ __forceinline__ unsigned bf16_rne(float f) {
    unsigned u = __float_as_uint(f);
    return (u + 0x7fffu + ((u >> 16) & 1u)) >> 16;
}
__device__ __forceinline__ float bf16_to_f(unsigned h) {
    return __uint_as_float(h << 16);
}

// ---------------------------------------------------------------------------
// K0a: transpose + hi/lo-split w_in and w1 -> wT[n][k] bf16 pairs. grid=512.
// ---------------------------------------------------------------------------
__global__ __launch_bounds__(256) void k0_wsplit(
    const float* __restrict__ w_in, const float* __restrict__ w1,
    u16* __restrict__ wiT_hi, u16* __restrict__ wiT_lo,
    u16* __restrict__ w1T_hi, u16* __restrict__ w1T_lo)
{
    const int n = blockIdx.x & 255, which = blockIdx.x >> 8;
    const float* w = which ? w1 : w_in;
    u16* th = which ? w1T_hi : wiT_hi;
    u16* tl = which ? w1T_lo : wiT_lo;
    for (int k = threadIdx.x; k < DIM; k += 256) {
        float v = w[(size_t)k * DH + n];
        unsigned hi = bf16_rne(v);
        unsigned lo = bf16_rne(v - bf16_to_f(hi));
        th[(size_t)n * DIM + k] = (u16)hi;
        tl[(size_t)n * DIM + k] = (u16)lo;
    }
}

// ---------------------------------------------------------------------------
// K0b: LN + hi/lo split of x -> xs_hi/xs_lo (padded rows duplicate row 196).
// One wave per row; grid = MTOT/4.
// ---------------------------------------------------------------------------
__global__ __launch_bounds__(256) void k0_ln_split(
    const float* __restrict__ x, const float* __restrict__ gamma,
    const float* __restrict__ beta,
    u16* __restrict__ xs_hi, u16* __restrict__ xs_lo)
{
    const int row  = blockIdx.x * 4 + (threadIdx.x >> 6);
    const int lane = threadIdx.x & 63;
    const int f = row / MPAD;
    int rr = row - f * MPAD; if (rr > NTOK - 1) rr = NTOK - 1;
    const float* xr = x + ((size_t)f * NTOK + rr) * DIM + lane * 8;
    float4 a = *(const float4*)xr, b4 = *(const float4*)(xr + 4);
    float e[8] = {a.x, a.y, a.z, a.w, b4.x, b4.y, b4.z, b4.w};
    float s = 0.f, sq = 0.f;
    #pragma unroll
    for (int j = 0; j < 8; ++j) { s += e[j]; sq += e[j] * e[j]; }
    #pragma unroll
    for (int o = 32; o > 0; o >>= 1) {
        s  += __shfl_xor(s,  o, 64);
        sq += __shfl_xor(sq, o, 64);
    }
    const float mu  = s * (1.f / 512.f);
    const float var = sq * (1.f / 512.f) - mu * mu;
    const float rs  = 1.f / sqrtf(var + 1e-5f);

    const float* gp = gamma + lane * 8;
    const float* bp = beta + lane * 8;
    float4 g0 = *(const float4*)gp, g1 = *(const float4*)(gp + 4);
    float4 b0 = *(const float4*)bp, b1 = *(const float4*)(bp + 4);
    float gg[8] = {g0.x, g0.y, g0.z, g0.w, g1.x, g1.y, g1.z, g1.w};
    float bt[8] = {b0.x, b0.y, b0.z, b0.w, b1.x, b1.y, b1.z, b1.w};

    unsigned hw[4], lw[4];
    #pragma unroll
    for (int p = 0; p < 4; ++p) {
        float s0 = rs * gg[2*p],   s1 = rs * gg[2*p+1];
        float v0 = e[2*p]   * s0 + (bt[2*p]   - mu * s0);
        float v1 = e[2*p+1] * s1 + (bt[2*p+1] - mu * s1);
        unsigned h0 = bf16_rne(v0), h1 = bf16_rne(v1);
        float l0 = v0 - bf16_to_f(h0), l1 = v1 - bf16_to_f(h1);
        hw[p] = h0 | (h1 << 16);
        lw[p] = bf16_rne(l0) | (bf16_rne(l1) << 16);
    }
    size_t off = (size_t)row * DIM + lane * 8;
    *(uint4*)(xs_hi + off) = make_uint4(hw[0], hw[1], hw[2], hw[3]);
    *(uint4*)(xs_lo + off) = make_uint4(lw[0], lw[1], lw[2], lw[3]);
}

// ---------------------------------------------------------------------------
// K1a: h = gelu(xs @ w_in) via 3-term bf16-split MFMA. Pure-copy staging.
// Tile 128(M) x 64(N), BK=32, grid = 156*4 = 624, 4 waves of 64x32.
// LDS 30.7 KB -> ~2.4 blocks/CU resident.
// ---------------------------------------------------------------------------
#define LDG 40
__global__ __launch_bounds__(256, 4) void k1_gemm1(
    const u16* __restrict__ xs_hi, const u16* __restrict__ xs_lo,
    const u16* __restrict__ wiT_hi, const u16* __restrict__ wiT_lo,
    u16* __restrict__ h_hi, u16* __restrict__ h_lo)
{
    __shared__ u16 Ah[128][LDG], Al[128][LDG], Bh[64][LDG], Bl[64][LDG];
    const int t = threadIdx.x, lane = t & 63, wv = t >> 6;
    const int Mb = blockIdx.x >> 2, Nb = blockIdx.x & 3;
    const int R0 = Mb * 128, N0 = Nb * 64;
    const int wm = wv >> 1, wn = wv & 1;           // wave: rows wm*64, cols wn*32
    const int m15 = lane & 15, q = lane >> 4;

    f32x4 acc[4][2];
    #pragma unroll
    for (int i = 0; i < 4; ++i)
        #pragma unroll
        for (int j = 0; j < 2; ++j)
            acc[i][j] = (f32x4){0.f, 0.f, 0.f, 0.f};

    const int ar = t >> 1, as = (t & 1) * 16;      // A: 2 thr/row, 16 u16 each
    const int br = t >> 2, bs = (t & 3) * 8;       // B: 4 thr/row, 8 u16 each
    const size_t abase = (size_t)(R0 + ar) * DIM + as;
    const size_t bbase = (size_t)(N0 + br) * DIM + bs;

    for (int k0 = 0; k0 < DIM; k0 += 32) {
        __syncthreads();
        *(uint4*)&Ah[ar][as]     = *(const uint4*)(xs_hi + abase + k0);
        *(uint4*)&Ah[ar][as + 8] = *(const uint4*)(xs_hi + abase + k0 + 8);
        *(uint4*)&Al[ar][as]     = *(const uint4*)(xs_lo + abase + k0);
        *(uint4*)&Al[ar][as + 8] = *(const uint4*)(xs_lo + abase + k0 + 8);
        *(uint4*)&Bh[br][bs]     = *(const uint4*)(wiT_hi + bbase + k0);
        *(uint4*)&Bl[br][bs]     = *(const uint4*)(wiT_lo + bbase + k0);
        __syncthreads();

        const int ko = q * 8;
        bf16x8 ah[4], al[4], bh[2], bl[2];
        #pragma unroll
        for (int i = 0; i < 4; ++i) {
            ah[i] = *(const bf16x8*)&Ah[wm*64 + i*16 + m15][ko];
            al[i] = *(const bf16x8*)&Al[wm*64 + i*16 + m15][ko];
        }
        #pragma unroll
        for (int i = 0; i < 2; ++i) {
            bh[i] = *(const bf16x8*)&Bh[wn*32 + i*16 + m15][ko];
            bl[i] = *(const bf16x8*)&Bl[wn*32 + i*16 + m15][ko];
        }
        #pragma unroll
        for (int mt = 0; mt < 4; ++mt)
            #pragma unroll
            for (int nt = 0; nt < 2; ++nt) {
                f32x4 c = acc[mt][nt];
                c = __builtin_amdgcn_mfma_f32_16x16x32_bf16(ah[mt], bh[nt], c, 0, 0, 0);
                c = __builtin_amdgcn_mfma_f32_16x16x32_bf16(al[mt], bh[nt], c, 0, 0, 0);
                c = __builtin_amdgcn_mfma_f32_16x16x32_bf16(ah[mt], bl[nt], c, 0, 0, 0);
                acc[mt][nt] = c;
            }
    }

    #pragma unroll
    for (int mt = 0; mt < 4; ++mt)
        #pragma unroll
        for (int nt = 0; nt < 2; ++nt)
            #pragma unroll
            for (int reg = 0; reg < 4; ++reg) {
                int r = R0 + wm*64 + mt*16 + q*4 + reg;
                int c = N0 + wn*32 + nt*16 + m15;
                float v = gelu_exact(acc[mt][nt][reg]);
                unsigned hb = bf16_rne(v);
                unsigned lb = bf16_rne(v - bf16_to_f(hb));
                size_t off = (size_t)r * DH + c;
                h_hi[off] = (u16)hb;
                h_lo[off] = (u16)lb;
            }
}

// ---------------------------------------------------------------------------
// K1b: s2 = [h|g] @ w1, partial-N score epilogue -> s_half[Nb][row].
// Tile 64(M) x 128(N-half), K=512, BK=32, grid = 312*2 = 624, waves 32x64.
// k2 finishes with tanh(sA+sB).
// ---------------------------------------------------------------------------
__global__ __launch_bounds__(256, 4) void k1_gemm2(
    const u16* __restrict__ h_hi, const u16* __restrict__ h_lo,
    const u16* __restrict__ w1T_hi, const u16* __restrict__ w1T_lo,
    const float* __restrict__ w2, float* __restrict__ s_half)
{
    __shared__ u16 Ah[64][LDG], Al[64][LDG], Bh[128][LDG], Bl[128][LDG];
    __shared__ float red[2][2][32];
    const int t = threadIdx.x, lane = t & 63, wv = t >> 6;
    const int Mb = blockIdx.x >> 1, Nb = blockIdx.x & 1;
    const int R0 = Mb * 64, N0 = Nb * 128;
    const int wm = wv >> 1, wn = wv & 1;           // wave: rows wm*32, cols wn*64
    const int m15 = lane & 15, q = lane >> 4;

    f32x4 acc[2][4];
    #pragma unroll
    for (int i = 0; i < 2; ++i)
        #pragma unroll
        for (int j = 0; j < 4; ++j)
            acc[i][j] = (f32x4){0.f, 0.f, 0.f, 0.f};

    const int ar = t >> 2, as = (t & 3) * 8;       // A: 4 thr/row, 8 u16
    const int agrow = R0 + ar;
    const size_t arow_off = (size_t)agrow * DH;
    const size_t g0_off   = (size_t)((agrow / MPAD) * MPAD) * DH;  // frame row-0 h
    const int br = t >> 1, bs = (t & 1) * 16;      // B: 2 thr/row, 16 u16
    const size_t bbase = (size_t)(N0 + br) * DIM + bs;

    for (int k0 = 0; k0 < DIM; k0 += 32) {
        __syncthreads();
        {
            size_t src = (k0 < DH) ? (arow_off + k0 + as)
                                   : (g0_off + (k0 - DH) + as);
            *(uint4*)&Ah[ar][as] = *(const uint4*)(h_hi + src);
            *(uint4*)&Al[ar][as] = *(const uint4*)(h_lo + src);
        }
        *(uint4*)&Bh[br][bs]     = *(const uint4*)(w1T_hi + bbase + k0);
        *(uint4*)&Bh[br][bs + 8] = *(const uint4*)(w1T_hi + bbase + k0 + 8);
        *(uint4*)&Bl[br][bs]     = *(const uint4*)(w1T_lo + bbase + k0);
        *(uint4*)&Bl[br][bs + 8] = *(const uint4*)(w1T_lo + bbase + k0 + 8);
        __syncthreads();

        const int ko = q * 8;
        bf16x8 ah[2], al[2], bh[4], bl[4];
        #pragma unroll
        for (int i = 0; i < 2; ++i) {
            ah[i] = *(const bf16x8*)&Ah[wm*32 + i*16 + m15][ko];
            al[i] = *(const bf16x8*)&Al[wm*32 + i*16 + m15][ko];
        }
        #pragma unroll
        for (int i = 0; i < 4; ++i) {
            bh[i] = *(const bf16x8*)&Bh[wn*64 + i*16 + m15][ko];
            bl[i] = *(const bf16x8*)&Bl[wn*64 + i*16 + m15][ko];
        }
        #pragma unroll
        for (int mt = 0; mt < 2; ++mt)
            #pragma unroll
            for (int nt = 0; nt < 4; ++nt) {
                f32x4 c = acc[mt][nt];
                c = __builtin_amdgcn_mfma_f32_16x16x32_bf16(ah[mt], bh[nt], c, 0, 0, 0);
                c = __builtin_amdgcn_mfma_f32_16x16x32_bf16(al[mt], bh[nt], c, 0, 0, 0);
                c = __builtin_amdgcn_mfma_f32_16x16x32_bf16(ah[mt], bl[nt], c, 0, 0, 0);
                acc[mt][nt] = c;
            }
    }

    // partial-N epilogue: gelu -> .w2 -> reduce over this block's 128 cols
    float w2v[4];
    #pragma unroll
    for (int nt = 0; nt < 4; ++nt) w2v[nt] = w2[N0 + wn*64 + nt*16 + m15];
    #pragma unroll
    for (int mt = 0; mt < 2; ++mt)
        #pragma unroll
        for (int reg = 0; reg < 4; ++reg) {
            float s = 0.f;
            #pragma unroll
            for (int nt = 0; nt < 4; ++nt)
                s += gelu_exact(acc[mt][nt][reg]) * w2v[nt];
            #pragma unroll
            for (int o = 1; o <= 8; o <<= 1)
                s += __shfl_xor(s, o, 64);
            if (m15 == 0)
                red[wn][wm][mt*16 + q*4 + reg] = s;
        }
    __syncthreads();
    if (t < 64) {
        int wmj = t >> 5, rl = t & 31;
        float sv = red[0][wmj][rl] + red[1][wmj][rl];
        s_half[(size_t)Nb * MTOT + R0 + t] = sv;
    }
}

// ---------------------------------------------------------------------------
// K2: top-49 radix descent, LDS histogram; score = tanh(sA+sB) inline.
// grid = 192, block = 1024 (16 waves, 8 samples/wave).
// ---------------------------------------------------------------------------
__global__ __launch_bounds__(1024) void k2_select(
    const float* __restrict__ s_half, const float* __restrict__ noise,
    int* __restrict__ hist2)
{
    const int fb   = blockIdx.x;
    const int f    = fb >> 1;
    const int half = fb & 1;
    const int t    = threadIdx.x;
    const int lane = t & 63;
    const int wv   = t >> 6;

    __shared__ int hist_s[KSEL * NSPAT];  // 38.4 KB
    for (int i = t; i < KSEL * NSPAT; i += 1024) hist_s[i] = 0;

    const float* sA = s_half;
    const float* sB = s_half + MTOT;
    float spv[4];
    #pragma unroll
    for (int j = 0; j < 4; ++j) {
        int l = lane + 64 * j;
        if (l < NSPAT) {
            size_t idx = (size_t)f * MPAD + 1 + l;
            spv[j] = tanhf(sA[idx] + sB[idx]);
        } else spv[j] = 0.f;
    }
    __syncthreads();

    const unsigned long long lmask = (1ull << lane) - 1ull;

    for (int si = 0; si < 8; ++si) {
        const int s = half * 128 + wv * 8 + si;
        const float* nz = noise + ((size_t)f * NSAMP + s) * NSPAT;
        unsigned key[4];
        #pragma unroll
        for (int j = 0; j < 4; ++j) {
            int l = lane + 64 * j;
            if (l < NSPAT) {
                float p = spv[j] + nz[l] * SIG;
                unsigned u = __float_as_uint(p);
                key[j] = (u & 0x80000000u) ? ~u : (u | 0x80000000u);
            } else {
                key[j] = 0u;
            }
        }

        unsigned ans = 0u;
        for (int bit = 31; bit >= 0; --bit) {
            unsigned cand = ans | (1u << bit);
            int cnt = 0;
            #pragma unroll
            for (int j = 0; j < 4; ++j)
                cnt += __popcll(__ballot(key[j] >= cand));
            if (cnt >= KSEL) ans = cand;
        }

        unsigned long long eq[4];
        int cgt = 0;
        #pragma unroll
        for (int j = 0; j < 4; ++j) {
            cgt += __popcll(__ballot(key[j] > ans));
            eq[j] = __ballot(key[j] == ans);
        }
        const int quota = KSEL - cgt;
        int eqpre[4]; { int run = 0;
            #pragma unroll
            for (int j = 0; j < 4; ++j) { eqpre[j] = run; run += __popcll(eq[j]); } }

        int pre = 0;
        #pragma unroll
        for (int j = 0; j < 4; ++j) {
            bool iseq = (key[j] == ans);
            int trk = eqpre[j] + __popcll(eq[j] & lmask);
            bool selj = (key[j] > ans) || (iseq && trk < quota);
            unsigned long long sb = __ballot(selj);
            int rk = pre + __popcll(sb & lmask);
            if (selj)
                atomicAdd(&hist_s[rk * NSPAT + lane + 64 * j], 1);
            pre += __popcll(sb);
        }
    }

    __syncthreads();
    int* hb = hist2 + (size_t)fb * (KSEL * NSPAT);
    for (int i = t; i < KSEL * NSPAT; i += 1024)
        hb[i] = hist_s[i];
}

// ---------------------------------------------------------------------------
// K3: out = [cls | (hist/256) @ spat]; sums the 2 per-half hist copies.
// ---------------------------------------------------------------------------
__global__ __launch_bounds__(256) void k3_output(
    const float* __restrict__ x, const int* __restrict__ hist2,
    float* __restrict__ out)
{
    const int b  = blockIdx.x >> 2;
    const int ds = blockIdx.x & 3;
    const int d0 = ds * 128;
    const int t  = threadIdx.x;
    const int tdc = t & 31;
    const int tk  = t >> 5;

    __shared__ float hist_s[NSPAT * KSEL + 8];

    const int* h0 = hist2 + (size_t)(2 * b) * (KSEL * NSPAT);
    const int* h1 = h0 + KSEL * NSPAT;
    for (int i = t; i < KSEL * NSPAT; i += 256) {
        int k = i / NSPAT;
        int l = i - k * NSPAT;
        hist_s[l * KSEL + k] = (float)(h0[i] + h1[i]);
    }
    if (t < 128)
        out[(size_t)b * 50 * DIM + d0 + t] = x[(size_t)b * NTOK * DIM + d0 + t];
    __syncthreads();

    const float* xs = x + ((size_t)b * NTOK + 1) * DIM + d0 + tdc * 4;
    float4 acc[7];
    #pragma unroll
    for (int i = 0; i < 7; ++i) acc[i] = make_float4(0.f, 0.f, 0.f, 0.f);

    #pragma unroll 2
    for (int l = 0; l < NSPAT; ++l) {
        float4 v = *(const float4*)(xs + (size_t)l * DIM);
        const float* hl = &hist_s[l * KSEL + tk];
        #pragma unroll
        for (int i = 0; i < 7; ++i) {
            float w = hl[8 * i];
            acc[i].x += w * v.x; acc[i].y += w * v.y;
            acc[i].z += w * v.z; acc[i].w += w * v.w;
        }
    }

    const float inv = 1.f / 256.f;
    #pragma unroll
    for (int i = 0; i < 7; ++i) {
        int k = tk + 8 * i;
        if (k < KSEL) {
            float4 o = make_float4(acc[i].x * inv, acc[i].y * inv,
                                   acc[i].z * inv, acc[i].w * inv);
            *(float4*)&out[((size_t)b * 50 + 1 + k) * DIM + d0 + tdc * 4] = o;
        }
    }
}

// ---------------------------------------------------------------------------
extern "C" void kernel_launch(void* const* d_in, const int* in_sizes, int n_in,
                              void* d_out, int out_size, void* d_ws, size_t ws_size,
                              hipStream_t stream)
{
    const float* x     = (const float*)d_in[0];
    const float* noise = (const float*)d_in[1];
    const float* gamma = (const float*)d_in[2];
    const float* beta  = (const float*)d_in[3];
    const float* w_in  = (const float*)d_in[4];
    const float* w1    = (const float*)d_in[5];
    const float* w2    = (const float*)d_in[6];
    float* out = (float*)d_out;

    // ws layout (bytes; total ~66.7 MB)
    char* ws = (char*)d_ws;
    int*   hist2   = (int*)  (ws + 0);            // 192*49*196*4 = 7,375,872
    float* s_half  = (float*)(ws + 7375872);      // 2*19968*4    =   159,744
    u16*   wiT_hi  = (u16*)  (ws + 7535616);      // 256*512*2    =   262,144
    u16*   wiT_lo  = (u16*)  (ws + 7797760);
    u16*   w1T_hi  = (u16*)  (ws + 8059904);
    u16*   w1T_lo  = (u16*)  (ws + 8322048);
    u16*   h_hi    = (u16*)  (ws + 8584192);      // 19968*256*2  = 10,223,616
    u16*   h_lo    = (u16*)  (ws + 18807808);
    u16*   xs_hi   = (u16*)  (ws + 29031424);     // 19968*512*2  = 20,447,232
    u16*   xs_lo   = (u16*)  (ws + 49478656);     // end 69,925,888

    k0_wsplit<<<512, 256, 0, stream>>>(w_in, w1, wiT_hi, wiT_lo, w1T_hi, w1T_lo);
    k0_ln_split<<<MTOT / 4, 256, 0, stream>>>(x, gamma, beta, xs_hi, xs_lo);
    k1_gemm1<<<(MTOT / 128) * 4, 256, 0, stream>>>(xs_hi, xs_lo, wiT_hi, wiT_lo,
                                                   h_hi, h_lo);
    k1_gemm2<<<(MTOT / 64) * 2, 256, 0, stream>>>(h_hi, h_lo, w1T_hi, w1T_lo,
                                                  w2, s_half);
    k2_select<<<NFRAME * 2, 1024, 0, stream>>>(s_half, noise, hist2);
    k3_output<<<NFRAME * 4, 256, 0, stream>>>(x, hist2, out);
}

// Round 6
// 234.074 us; speedup vs baseline: 5.4752x; 1.0595x over previous
//
#include <hip/hip_runtime.h>
#include <math.h>

#define NFRAME 96
#define NTOK   197
#define NSPAT  196
#define DIM    512
#define DH     256
#define NSAMP  256
#define KSEL   49
#define SIG    0.05f
#define MPAD   208                 // padded rows per frame
#define MTOT   (NFRAME * MPAD)     // 19968 = 156*128

typedef unsigned short u16;
typedef __attribute__((ext_vector_type(8))) short bf16x8;   // 8 bf16 (4 VGPRs)
typedef __attribute__((ext_vector_type(4))) float f32x4;

__device__ __forceinline__ float gelu_exact(float v) {
    return 0.5f * v * (1.0f + erff(v * 0.70710678118654752440f));
}
__device__ __forceinline__ unsigned bf16_rne(float f) {
    unsigned u = __float_as_uint(f);
    return (u + 0x7fffu + ((u >> 16) & 1u)) >> 16;
}
__device__ __forceinline__ float bf16_to_f(unsigned h) {
    return __uint_as_float(h << 16);
}

// ---------------------------------------------------------------------------
// K0: fused prep. blocks [0,512): weight transpose+split. blocks [512,...):
// LN + hi/lo split of x (one wave per padded row).
// ---------------------------------------------------------------------------
__global__ __launch_bounds__(256) void k0_prep(
    const float* __restrict__ x, const float* __restrict__ gamma,
    const float* __restrict__ beta,
    const float* __restrict__ w_in, const float* __restrict__ w1,
    u16* __restrict__ wiT_hi, u16* __restrict__ wiT_lo,
    u16* __restrict__ w1T_hi, u16* __restrict__ w1T_lo,
    u16* __restrict__ xs_hi, u16* __restrict__ xs_lo)
{
    if (blockIdx.x < 512) {
        const int n = blockIdx.x & 255, which = blockIdx.x >> 8;
        const float* w = which ? w1 : w_in;
        u16* th = which ? w1T_hi : wiT_hi;
        u16* tl = which ? w1T_lo : wiT_lo;
        for (int k = threadIdx.x; k < DIM; k += 256) {
            float v = w[(size_t)k * DH + n];
            unsigned hi = bf16_rne(v);
            unsigned lo = bf16_rne(v - bf16_to_f(hi));
            th[(size_t)n * DIM + k] = (u16)hi;
            tl[(size_t)n * DIM + k] = (u16)lo;
        }
        return;
    }
    const int row  = (blockIdx.x - 512) * 4 + (threadIdx.x >> 6);
    const int lane = threadIdx.x & 63;
    const int f = row / MPAD;
    int rr = row - f * MPAD; if (rr > NTOK - 1) rr = NTOK - 1;
    const float* xr = x + ((size_t)f * NTOK + rr) * DIM + lane * 8;
    float4 a = *(const float4*)xr, b4 = *(const float4*)(xr + 4);
    float e[8] = {a.x, a.y, a.z, a.w, b4.x, b4.y, b4.z, b4.w};
    float s = 0.f, sq = 0.f;
    #pragma unroll
    for (int j = 0; j < 8; ++j) { s += e[j]; sq += e[j] * e[j]; }
    #pragma unroll
    for (int o = 32; o > 0; o >>= 1) {
        s  += __shfl_xor(s,  o, 64);
        sq += __shfl_xor(sq, o, 64);
    }
    const float mu  = s * (1.f / 512.f);
    const float var = sq * (1.f / 512.f) - mu * mu;
    const float rs  = 1.f / sqrtf(var + 1e-5f);

    const float* gp = gamma + lane * 8;
    const float* bp = beta + lane * 8;
    float4 g0 = *(const float4*)gp, g1 = *(const float4*)(gp + 4);
    float4 b0 = *(const float4*)bp, b1 = *(const float4*)(bp + 4);
    float gg[8] = {g0.x, g0.y, g0.z, g0.w, g1.x, g1.y, g1.z, g1.w};
    float bt[8] = {b0.x, b0.y, b0.z, b0.w, b1.x, b1.y, b1.z, b1.w};

    unsigned hw[4], lw[4];
    #pragma unroll
    for (int p = 0; p < 4; ++p) {
        float s0 = rs * gg[2*p],   s1 = rs * gg[2*p+1];
        float v0 = e[2*p]   * s0 + (bt[2*p]   - mu * s0);
        float v1 = e[2*p+1] * s1 + (bt[2*p+1] - mu * s1);
        unsigned h0 = bf16_rne(v0), h1 = bf16_rne(v1);
        float l0 = v0 - bf16_to_f(h0), l1 = v1 - bf16_to_f(h1);
        hw[p] = h0 | (h1 << 16);
        lw[p] = bf16_rne(l0) | (bf16_rne(l1) << 16);
    }
    size_t off = (size_t)row * DIM + lane * 8;
    *(uint4*)(xs_hi + off) = make_uint4(hw[0], hw[1], hw[2], hw[3]);
    *(uint4*)(xs_lo + off) = make_uint4(lw[0], lw[1], lw[2], lw[3]);
}

// ---------------------------------------------------------------------------
// K1a: h = gelu(xs @ w_in), 3-term bf16-split MFMA, register-prefetch
// pipelined. Tile 128(M) x 64(N), BK=32, grid 624, XCD-swizzled so the 4
// N-blocks of one M-tile share an XCD (A-slice served from that XCD's L2).
// ---------------------------------------------------------------------------
#define LDG 40
__global__ __launch_bounds__(256, 4) void k1_gemm1(
    const u16* __restrict__ xs_hi, const u16* __restrict__ xs_lo,
    const u16* __restrict__ wiT_hi, const u16* __restrict__ wiT_lo,
    u16* __restrict__ h_hi, u16* __restrict__ h_lo)
{
    __shared__ u16 Ah[128][LDG], Al[128][LDG], Bh[64][LDG], Bl[64][LDG];
    const int t = threadIdx.x, lane = t & 63, wv = t >> 6;
    // XCD swizzle: 624 blocks = 8 XCDs x 78; consecutive 'linear' on one XCD
    const int linear = (blockIdx.x & 7) * 78 + (blockIdx.x >> 3);
    const int Mb = linear >> 2, Nb = linear & 3;
    const int R0 = Mb * 128, N0 = Nb * 64;
    const int wm = wv >> 1, wn = wv & 1;
    const int m15 = lane & 15, q = lane >> 4;

    f32x4 acc[4][2];
    #pragma unroll
    for (int i = 0; i < 4; ++i)
        #pragma unroll
        for (int j = 0; j < 2; ++j)
            acc[i][j] = (f32x4){0.f, 0.f, 0.f, 0.f};

    const int ar = t >> 1, as = (t & 1) * 16;      // A: 2 thr/row, 16 u16 each
    const int br = t >> 2, bs = (t & 3) * 8;       // B: 4 thr/row, 8 u16 each
    const size_t abase = (size_t)(R0 + ar) * DIM + as;
    const size_t bbase = (size_t)(N0 + br) * DIM + bs;

    // prefetch k0 = 0
    uint4 pAh0 = *(const uint4*)(xs_hi + abase);
    uint4 pAh1 = *(const uint4*)(xs_hi + abase + 8);
    uint4 pAl0 = *(const uint4*)(xs_lo + abase);
    uint4 pAl1 = *(const uint4*)(xs_lo + abase + 8);
    uint4 pBh  = *(const uint4*)(wiT_hi + bbase);
    uint4 pBl  = *(const uint4*)(wiT_lo + bbase);

    for (int k0 = 0; k0 < DIM; k0 += 32) {
        __syncthreads();
        *(uint4*)&Ah[ar][as]     = pAh0;
        *(uint4*)&Ah[ar][as + 8] = pAh1;
        *(uint4*)&Al[ar][as]     = pAl0;
        *(uint4*)&Al[ar][as + 8] = pAl1;
        *(uint4*)&Bh[br][bs]     = pBh;
        *(uint4*)&Bl[br][bs]     = pBl;
        if (k0 + 32 < DIM) {   // issue next tile's loads; consumed next iter
            pAh0 = *(const uint4*)(xs_hi + abase + k0 + 32);
            pAh1 = *(const uint4*)(xs_hi + abase + k0 + 40);
            pAl0 = *(const uint4*)(xs_lo + abase + k0 + 32);
            pAl1 = *(const uint4*)(xs_lo + abase + k0 + 40);
            pBh  = *(const uint4*)(wiT_hi + bbase + k0 + 32);
            pBl  = *(const uint4*)(wiT_lo + bbase + k0 + 32);
        }
        __syncthreads();

        const int ko = q * 8;
        bf16x8 ah[4], al[4], bh[2], bl[2];
        #pragma unroll
        for (int i = 0; i < 4; ++i) {
            ah[i] = *(const bf16x8*)&Ah[wm*64 + i*16 + m15][ko];
            al[i] = *(const bf16x8*)&Al[wm*64 + i*16 + m15][ko];
        }
        #pragma unroll
        for (int i = 0; i < 2; ++i) {
            bh[i] = *(const bf16x8*)&Bh[wn*32 + i*16 + m15][ko];
            bl[i] = *(const bf16x8*)&Bl[wn*32 + i*16 + m15][ko];
        }
        #pragma unroll
        for (int mt = 0; mt < 4; ++mt)
            #pragma unroll
            for (int nt = 0; nt < 2; ++nt) {
                f32x4 c = acc[mt][nt];
                c = __builtin_amdgcn_mfma_f32_16x16x32_bf16(ah[mt], bh[nt], c, 0, 0, 0);
                c = __builtin_amdgcn_mfma_f32_16x16x32_bf16(al[mt], bh[nt], c, 0, 0, 0);
                c = __builtin_amdgcn_mfma_f32_16x16x32_bf16(ah[mt], bl[nt], c, 0, 0, 0);
                acc[mt][nt] = c;
            }
    }

    #pragma unroll
    for (int mt = 0; mt < 4; ++mt)
        #pragma unroll
        for (int nt = 0; nt < 2; ++nt)
            #pragma unroll
            for (int reg = 0; reg < 4; ++reg) {
                int r = R0 + wm*64 + mt*16 + q*4 + reg;
                int c = N0 + wn*32 + nt*16 + m15;
                float v = gelu_exact(acc[mt][nt][reg]);
                unsigned hb = bf16_rne(v);
                unsigned lb = bf16_rne(v - bf16_to_f(hb));
                size_t off = (size_t)r * DH + c;
                h_hi[off] = (u16)hb;
                h_lo[off] = (u16)lb;
            }
}

// ---------------------------------------------------------------------------
// K1b: s2 = [h|g] @ w1, partial-N score epilogue -> s_half[Nb][row].
// Tile 64(M) x 128(N-half), BK=32, grid 624, XCD-swizzled, reg-prefetch.
// ---------------------------------------------------------------------------
__global__ __launch_bounds__(256, 4) void k1_gemm2(
    const u16* __restrict__ h_hi, const u16* __restrict__ h_lo,
    const u16* __restrict__ w1T_hi, const u16* __restrict__ w1T_lo,
    const float* __restrict__ w2, float* __restrict__ s_half)
{
    __shared__ u16 Ah[64][LDG], Al[64][LDG], Bh[128][LDG], Bl[128][LDG];
    __shared__ float red[2][2][32];
    const int t = threadIdx.x, lane = t & 63, wv = t >> 6;
    const int linear = (blockIdx.x & 7) * 78 + (blockIdx.x >> 3);
    const int Mb = linear >> 1, Nb = linear & 1;
    const int R0 = Mb * 64, N0 = Nb * 128;
    const int wm = wv >> 1, wn = wv & 1;
    const int m15 = lane & 15, q = lane >> 4;

    f32x4 acc[2][4];
    #pragma unroll
    for (int i = 0; i < 2; ++i)
        #pragma unroll
        for (int j = 0; j < 4; ++j)
            acc[i][j] = (f32x4){0.f, 0.f, 0.f, 0.f};

    const int ar = t >> 2, as = (t & 3) * 8;       // A: 4 thr/row, 8 u16
    const int agrow = R0 + ar;
    const size_t arow_off = (size_t)agrow * DH;
    const size_t g0_off   = (size_t)((agrow / MPAD) * MPAD) * DH;
    const int br = t >> 1, bs = (t & 1) * 16;      // B: 2 thr/row, 16 u16
    const size_t bbase = (size_t)(N0 + br) * DIM + bs;

    auto asrc = [&](int k0) -> size_t {
        return (k0 < DH) ? (arow_off + k0 + as) : (g0_off + (k0 - DH) + as);
    };

    uint4 pAh = *(const uint4*)(h_hi + asrc(0));
    uint4 pAl = *(const uint4*)(h_lo + asrc(0));
    uint4 pBh0 = *(const uint4*)(w1T_hi + bbase);
    uint4 pBh1 = *(const uint4*)(w1T_hi + bbase + 8);
    uint4 pBl0 = *(const uint4*)(w1T_lo + bbase);
    uint4 pBl1 = *(const uint4*)(w1T_lo + bbase + 8);

    for (int k0 = 0; k0 < DIM; k0 += 32) {
        __syncthreads();
        *(uint4*)&Ah[ar][as]     = pAh;
        *(uint4*)&Al[ar][as]     = pAl;
        *(uint4*)&Bh[br][bs]     = pBh0;
        *(uint4*)&Bh[br][bs + 8] = pBh1;
        *(uint4*)&Bl[br][bs]     = pBl0;
        *(uint4*)&Bl[br][bs + 8] = pBl1;
        if (k0 + 32 < DIM) {
            size_t srcn = asrc(k0 + 32);
            pAh  = *(const uint4*)(h_hi + srcn);
            pAl  = *(const uint4*)(h_lo + srcn);
            pBh0 = *(const uint4*)(w1T_hi + bbase + k0 + 32);
            pBh1 = *(const uint4*)(w1T_hi + bbase + k0 + 40);
            pBl0 = *(const uint4*)(w1T_lo + bbase + k0 + 32);
            pBl1 = *(const uint4*)(w1T_lo + bbase + k0 + 40);
        }
        __syncthreads();

        const int ko = q * 8;
        bf16x8 ah[2], al[2], bh[4], bl[4];
        #pragma unroll
        for (int i = 0; i < 2; ++i) {
            ah[i] = *(const bf16x8*)&Ah[wm*32 + i*16 + m15][ko];
            al[i] = *(const bf16x8*)&Al[wm*32 + i*16 + m15][ko];
        }
        #pragma unroll
        for (int i = 0; i < 4; ++i) {
            bh[i] = *(const bf16x8*)&Bh[wn*64 + i*16 + m15][ko];
            bl[i] = *(const bf16x8*)&Bl[wn*64 + i*16 + m15][ko];
        }
        #pragma unroll
        for (int mt = 0; mt < 2; ++mt)
            #pragma unroll
            for (int nt = 0; nt < 4; ++nt) {
                f32x4 c = acc[mt][nt];
                c = __builtin_amdgcn_mfma_f32_16x16x32_bf16(ah[mt], bh[nt], c, 0, 0, 0);
                c = __builtin_amdgcn_mfma_f32_16x16x32_bf16(al[mt], bh[nt], c, 0, 0, 0);
                c = __builtin_amdgcn_mfma_f32_16x16x32_bf16(ah[mt], bl[nt], c, 0, 0, 0);
                acc[mt][nt] = c;
            }
    }

    float w2v[4];
    #pragma unroll
    for (int nt = 0; nt < 4; ++nt) w2v[nt] = w2[N0 + wn*64 + nt*16 + m15];
    #pragma unroll
    for (int mt = 0; mt < 2; ++mt)
        #pragma unroll
        for (int reg = 0; reg < 4; ++reg) {
            float s = 0.f;
            #pragma unroll
            for (int nt = 0; nt < 4; ++nt)
                s += gelu_exact(acc[mt][nt][reg]) * w2v[nt];
            #pragma unroll
            for (int o = 1; o <= 8; o <<= 1)
                s += __shfl_xor(s, o, 64);
            if (m15 == 0)
                red[wn][wm][mt*16 + q*4 + reg] = s;
        }
    __syncthreads();
    if (t < 64) {
        int wmj = t >> 5, rl = t & 31;
        float sv = red[0][wmj][rl] + red[1][wmj][rl];
        s_half[(size_t)Nb * MTOT + R0 + t] = sv;
    }
}

// ---------------------------------------------------------------------------
// K2: top-49 radix descent, LDS histogram; score = tanh(sA+sB) inline.
// grid = 192, block = 1024 (16 waves, 8 samples/wave).
// ---------------------------------------------------------------------------
__global__ __launch_bounds__(1024) void k2_select(
    const float* __restrict__ s_half, const float* __restrict__ noise,
    int* __restrict__ hist2)
{
    const int fb   = blockIdx.x;
    const int f    = fb >> 1;
    const int half = fb & 1;
    const int t    = threadIdx.x;
    const int lane = t & 63;
    const int wv   = t >> 6;

    __shared__ int hist_s[KSEL * NSPAT];  // 38.4 KB
    for (int i = t; i < KSEL * NSPAT; i += 1024) hist_s[i] = 0;

    const float* sA = s_half;
    const float* sB = s_half + MTOT;
    float spv[4];
    #pragma unroll
    for (int j = 0; j < 4; ++j) {
        int l = lane + 64 * j;
        if (l < NSPAT) {
            size_t idx = (size_t)f * MPAD + 1 + l;
            spv[j] = tanhf(sA[idx] + sB[idx]);
        } else spv[j] = 0.f;
    }
    __syncthreads();

    const unsigned long long lmask = (1ull << lane) - 1ull;

    for (int si = 0; si < 8; ++si) {
        const int s = half * 128 + wv * 8 + si;
        const float* nz = noise + ((size_t)f * NSAMP + s) * NSPAT;
        unsigned key[4];
        #pragma unroll
        for (int j = 0; j < 4; ++j) {
            int l = lane + 64 * j;
            if (l < NSPAT) {
                float p = spv[j] + nz[l] * SIG;
                unsigned u = __float_as_uint(p);
                key[j] = (u & 0x80000000u) ? ~u : (u | 0x80000000u);
            } else {
                key[j] = 0u;
            }
        }

        unsigned ans = 0u;
        for (int bit = 31; bit >= 0; --bit) {
            unsigned cand = ans | (1u << bit);
            int cnt = 0;
            #pragma unroll
            for (int j = 0; j < 4; ++j)
                cnt += __popcll(__ballot(key[j] >= cand));
            if (cnt >= KSEL) ans = cand;
        }

        unsigned long long eq[4];
        int cgt = 0;
        #pragma unroll
        for (int j = 0; j < 4; ++j) {
            cgt += __popcll(__ballot(key[j] > ans));
            eq[j] = __ballot(key[j] == ans);
        }
        const int quota = KSEL - cgt;
        int eqpre[4]; { int run = 0;
            #pragma unroll
            for (int j = 0; j < 4; ++j) { eqpre[j] = run; run += __popcll(eq[j]); } }

        int pre = 0;
        #pragma unroll
        for (int j = 0; j < 4; ++j) {
            bool iseq = (key[j] == ans);
            int trk = eqpre[j] + __popcll(eq[j] & lmask);
            bool selj = (key[j] > ans) || (iseq && trk < quota);
            unsigned long long sb = __ballot(selj);
            int rk = pre + __popcll(sb & lmask);
            if (selj)
                atomicAdd(&hist_s[rk * NSPAT + lane + 64 * j], 1);
            pre += __popcll(sb);
        }
    }

    __syncthreads();
    int* hb = hist2 + (size_t)fb * (KSEL * NSPAT);
    for (int i = t; i < KSEL * NSPAT; i += 1024)
        hb[i] = hist_s[i];
}

// ---------------------------------------------------------------------------
// K3: out = [cls | (hist/256) @ spat]; sums the 2 per-half hist copies.
// ---------------------------------------------------------------------------
__global__ __launch_bounds__(256) void k3_output(
    const float* __restrict__ x, const int* __restrict__ hist2,
    float* __restrict__ out)
{
    const int b  = blockIdx.x >> 2;
    const int ds = blockIdx.x & 3;
    const int d0 = ds * 128;
    const int t  = threadIdx.x;
    const int tdc = t & 31;
    const int tk  = t >> 5;

    __shared__ float hist_s[NSPAT * KSEL + 8];

    const int* h0 = hist2 + (size_t)(2 * b) * (KSEL * NSPAT);
    const int* h1 = h0 + KSEL * NSPAT;
    for (int i = t; i < KSEL * NSPAT; i += 256) {
        int k = i / NSPAT;
        int l = i - k * NSPAT;
        hist_s[l * KSEL + k] = (float)(h0[i] + h1[i]);
    }
    if (t < 128)
        out[(size_t)b * 50 * DIM + d0 + t] = x[(size_t)b * NTOK * DIM + d0 + t];
    __syncthreads();

    const float* xs = x + ((size_t)b * NTOK + 1) * DIM + d0 + tdc * 4;
    float4 acc[7];
    #pragma unroll
    for (int i = 0; i < 7; ++i) acc[i] = make_float4(0.f, 0.f, 0.f, 0.f);

    #pragma unroll 2
    for (int l = 0; l < NSPAT; ++l) {
        float4 v = *(const float4*)(xs + (size_t)l * DIM);
        const float* hl = &hist_s[l * KSEL + tk];
        #pragma unroll
        for (int i = 0; i < 7; ++i) {
            float w = hl[8 * i];
            acc[i].x += w * v.x; acc[i].y += w * v.y;
            acc[i].z += w * v.z; acc[i].w += w * v.w;
        }
    }

    const float inv = 1.f / 256.f;
    #pragma unroll
    for (int i = 0; i < 7; ++i) {
        int k = tk + 8 * i;
        if (k < KSEL) {
            float4 o = make_float4(acc[i].x * inv, acc[i].y * inv,
                                   acc[i].z * inv, acc[i].w * inv);
            *(float4*)&out[((size_t)b * 50 + 1 + k) * DIM + d0 + tdc * 4] = o;
        }
    }
}

// ---------------------------------------------------------------------------
extern "C" void kernel_launch(void* const* d_in, const int* in_sizes, int n_in,
                              void* d_out, int out_size, void* d_ws, size_t ws_size,
                              hipStream_t stream)
{
    const float* x     = (const float*)d_in[0];
    const float* noise = (const float*)d_in[1];
    const float* gamma = (const float*)d_in[2];
    const float* beta  = (const float*)d_in[3];
    const float* w_in  = (const float*)d_in[4];
    const float* w1    = (const float*)d_in[5];
    const float* w2    = (const float*)d_in[6];
    float* out = (float*)d_out;

    // ws layout (bytes; total ~66.7 MB)
    char* ws = (char*)d_ws;
    int*   hist2   = (int*)  (ws + 0);            // 192*49*196*4 = 7,375,872
    float* s_half  = (float*)(ws + 7375872);      // 2*19968*4    =   159,744
    u16*   wiT_hi  = (u16*)  (ws + 7535616);      // 256*512*2    =   262,144
    u16*   wiT_lo  = (u16*)  (ws + 7797760);
    u16*   w1T_hi  = (u16*)  (ws + 8059904);
    u16*   w1T_lo  = (u16*)  (ws + 8322048);
    u16*   h_hi    = (u16*)  (ws + 8584192);      // 19968*256*2  = 10,223,616
    u16*   h_lo    = (u16*)  (ws + 18807808);
    u16*   xs_hi   = (u16*)  (ws + 29031424);     // 19968*512*2  = 20,447,232
    u16*   xs_lo   = (u16*)  (ws + 49478656);     // end 69,925,888

    k0_prep<<<512 + MTOT / 4, 256, 0, stream>>>(x, gamma, beta, w_in, w1,
                                                wiT_hi, wiT_lo, w1T_hi, w1T_lo,
                                                xs_hi, xs_lo);
    k1_gemm1<<<(MTOT / 128) * 4, 256, 0, stream>>>(xs_hi, xs_lo, wiT_hi, wiT_lo,
                                                   h_hi, h_lo);
    k1_gemm2<<<(MTOT / 64) * 2, 256, 0, stream>>>(h_hi, h_lo, w1T_hi, w1T_lo,
                                                  w2, s_half);
    k2_select<<<NFRAME * 2, 1024, 0, stream>>>(s_half, noise, hist2);
    k3_output<<<NFRAME * 4, 256, 0, stream>>>(x, hist2, out);
}